// Round 7
// baseline (959.593 us; speedup 1.0000x reference)
//
#include <hip/hip_runtime.h>

// Problem constants
constexpr int Bb = 2;
constexpr int Ll = 2048;
constexpr int Dd = 2048;
constexpr int Hh = 16;
constexpr int Hd = 128;
constexpr int M  = Bb * Ll;   // 4096

typedef __attribute__((ext_vector_type(8)))  short s16x8;   // 8 bf16 (4 VGPRs)
typedef __attribute__((ext_vector_type(4)))  float f32x4;   // 16x16 C/D
typedef __attribute__((ext_vector_type(16))) float f32x16;  // 32x32 C/D

__device__ __forceinline__ unsigned short f2bf(float f) {
    union { float f; unsigned u; } v; v.f = f;
    unsigned r = v.u + 0x7fffu + ((v.u >> 16) & 1u);   // RNE
    return (unsigned short)(r >> 16);
}
__device__ __forceinline__ float bf2f(unsigned short b) {
    union { unsigned u; float f; } v; v.u = ((unsigned)b) << 16;
    return v.f;
}
__device__ __forceinline__ float fast_exp2(float x) {
#if __has_builtin(__builtin_amdgcn_exp2f)
    return __builtin_amdgcn_exp2f(x);
#else
    return exp2f(x);
#endif
}

// async global->LDS, 16 B per lane; lds dest = wave-uniform base + lane*16
__device__ __forceinline__ void gld16(const void* g, void* l) {
#if __has_builtin(__builtin_amdgcn_global_load_lds)
    __builtin_amdgcn_global_load_lds(
        (const __attribute__((address_space(1))) unsigned int*)g,
        (__attribute__((address_space(3))) unsigned int*)l, 16, 0, 0);
#else
    int lane = threadIdx.x & 63;
    ((int4*)l)[lane] = ((const int4*)g)[0];
#endif
}

// ---------------------------------------------------------------------------
// fp32 -> bf16 conversion, all 5 tensors in ONE launch.
// Segments (exact 1024-elem blocks): X 8192 | wq 4096 | wk 4096 | wv 4096 |
// wo 4096 = 24576 blocks total.
// ---------------------------------------------------------------------------
__global__ __launch_bounds__(256)
void f2bf_all(const float* __restrict__ x,  const float* __restrict__ wq,
              const float* __restrict__ wk, const float* __restrict__ wv,
              const float* __restrict__ wo,
              unsigned short* __restrict__ Xb,  unsigned short* __restrict__ Wqb,
              unsigned short* __restrict__ Wkb, unsigned short* __restrict__ Wvb,
              unsigned short* __restrict__ Wob)
{
    int bid = blockIdx.x;
    const float* in; unsigned short* out; int off;
    if      (bid <  8192) { in = x;  out = Xb;  off = bid; }
    else if (bid < 12288) { in = wq; out = Wqb; off = bid - 8192; }
    else if (bid < 16384) { in = wk; out = Wkb; off = bid - 12288; }
    else if (bid < 20480) { in = wv; out = Wvb; off = bid - 16384; }
    else                  { in = wo; out = Wob; off = bid - 20480; }
    int i = (off * 256 + threadIdx.x) * 4;
    float4 v = *(const float4*)(in + i);
    ushort4 o;
    o.x = f2bf(v.x); o.y = f2bf(v.y); o.z = f2bf(v.z); o.w = f2bf(v.w);
    *(ushort4*)(out + i) = o;
}

// ---------------------------------------------------------------------------
// Fused QKV GEMM, A-direct-from-global (LDS-traffic cut):
// C = A * Wall^T.  A [4096][2048] bf16, Wall [6144][2048] (wq;wk;wv stacked).
// BM=128 x BN=192, BK=64, 256 threads = 4 waves (2M x 2N), per-wave 64x96.
// R6 post-mortem: LDS pipe (frag reads + staging writes) = ~1280 cyc/tile vs
// 466 MFMA -> LDS-BW-bound.  Fix: A-frags load STRAIGHT from global into
// registers (A row-major matches MFMA A-layout: row=r16, kchunk=q4; 16B/lane)
// -> removes 8/20 ds_reads and 16/40 KiB of LDS writes per tile; A flows via
// the L1/L2 pipe which overlaps the LDS pipe.  B stays LDS-staged (gld_lds,
// XOR-swizzled both-sides).  LDS = 2 x 24 KiB = 48 KiB -> 3 blocks/CU.
// Per tile: issue B-stage(t+1) FIRST, then 8 A-frag loads(t+1) into the
// alternate named reg buffer (2-tile unroll, rule-#20 static); 48 MFMA;
// counted vmcnt(8) (drains exactly the 6 oldest = B stages; A loads stay in
// flight, compiler's auto-waitcnt covers their first use); one barrier.
// Compiler fence between issue groups pins FIFO order (vmcnt soundness).
// Grid 32x32 = 1024 blocks.
// ---------------------------------------------------------------------------
__global__ __launch_bounds__(256, 3)
void mfma_gemm_qkv(const unsigned short* __restrict__ A,
                   const unsigned short* __restrict__ Wall,
                   unsigned short* __restrict__ Oq,
                   unsigned short* __restrict__ Ok,
                   unsigned short* __restrict__ Ov)
{
    constexpr int K  = 2048;
    constexpr int NT = K / 64;          // 32 K-tiles
    constexpr int BM = 128, BN = 192;
    constexpr int SLOT_US = BN * 64;    // 12288 ushorts = 24 KiB (B only)

    __shared__ unsigned short lds[2 * SLOT_US];   // 48 KiB -> 3 blocks/CU

    const int t    = threadIdx.x;
    const int w    = t >> 6, lane = t & 63;
    const int wm   = w >> 1, wn = w & 1;          // 2M x 2N
    const int m0   = blockIdx.y * BM, n0 = blockIdx.x * BN;
    const int r16  = lane & 15, q4 = lane >> 4;
    const int lxor = (r16 & 7) << 4;              // B read-side swizzle XOR

    // B staging lane constants: 8 lanes per 128B row; swizzled source column
    const int srow8 = lane >> 3;
    const int sgcol = (((lane & 7) ^ srow8) << 4);
    const char* Agb = (const char*)A;
    const char* Wgb = (const char*)Wall;

    const int c0 = (q4 * 16) ^ lxor;              // ksub0 byte col (swizzled)
    const int c1 = (64 + q4 * 16) ^ lxor;         // ksub1

    f32x4 acc[4][6];
#pragma unroll
    for (int i = 0; i < 4; ++i)
#pragma unroll
        for (int j = 0; j < 6; ++j)
            acc[i][j] = (f32x4){0.f, 0.f, 0.f, 0.f};

// B stage: 24 gld16/block (ib=w*6+p), 6 per wave
#define STAGE_B(tt, sl) do {                                                 \
    _Pragma("unroll") for (int p = 0; p < 6; ++p) {                          \
        int ib_ = w * 6 + p;                                                 \
        gld16(Wgb + (size_t)(n0 + ib_ * 8 + srow8) * (K * 2) + (tt) * 128 + sgcol, \
              &lds[(sl) * SLOT_US + ib_ * 512]);                             \
    } } while (0)

// A frags direct from global: dst[0..3]=ks0, dst[4..7]=ks1 (8 x 16B loads)
#define AFRAG_LOAD(dst, tt) do {                                             \
    _Pragma("unroll") for (int mi = 0; mi < 4; ++mi) {                       \
        const char* ap_ = Agb + (size_t)(m0 + wm * 64 + mi * 16 + r16) * (K * 2) \
                          + (tt) * 128 + q4 * 16;                            \
        dst[mi]     = *(const s16x8*)(ap_);                                  \
        dst[4 + mi] = *(const s16x8*)(ap_ + 64);                             \
    } } while (0)

// one K-tile: prefetch t+1 (B->LDS slot^1, A->aN regs), compute from aC+slot
#define TILE(tt, aC, aN) do {                                                \
    const int sl_ = (tt) & 1;                                                \
    if ((tt) + 1 < NT) {                                                     \
        STAGE_B((tt) + 1, sl_ ^ 1);                                          \
        asm volatile("" ::: "memory");      /* pin issue order: B before A */ \
        AFRAG_LOAD(aN, (tt) + 1);                                            \
        asm volatile("" ::: "memory");                                       \
    }                                                                        \
    const char* Bp_ = (const char*)&lds[sl_ * SLOT_US];                      \
    s16x8 bf_[6];                                                            \
    _Pragma("unroll") for (int ni = 0; ni < 6; ++ni)                         \
        bf_[ni] = *(const s16x8*)(Bp_ + (wn * 96 + ni * 16 + r16) * 128 + c0); \
    __builtin_amdgcn_s_setprio(1);                                           \
    _Pragma("unroll") for (int mi = 0; mi < 4; ++mi)                         \
    _Pragma("unroll") for (int ni = 0; ni < 6; ++ni)                         \
        acc[mi][ni] = __builtin_amdgcn_mfma_f32_16x16x32_bf16(                \
            aC[mi], bf_[ni], acc[mi][ni], 0, 0, 0);                          \
    __builtin_amdgcn_s_setprio(0);                                           \
    _Pragma("unroll") for (int ni = 0; ni < 6; ++ni)                         \
        bf_[ni] = *(const s16x8*)(Bp_ + (wn * 96 + ni * 16 + r16) * 128 + c1); \
    __builtin_amdgcn_s_setprio(1);                                           \
    _Pragma("unroll") for (int mi = 0; mi < 4; ++mi)                         \
    _Pragma("unroll") for (int ni = 0; ni < 6; ++ni)                         \
        acc[mi][ni] = __builtin_amdgcn_mfma_f32_16x16x32_bf16(                \
            aC[4 + mi], bf_[ni], acc[mi][ni], 0, 0, 0);                      \
    __builtin_amdgcn_s_setprio(0);                                           \
    if ((tt) + 1 < NT) {                                                     \
        asm volatile("s_waitcnt vmcnt(8)" ::: "memory"); /* 6 oldest = B */  \
        __builtin_amdgcn_s_barrier();                                        \
        asm volatile("" ::: "memory");                                       \
    }                                                                        \
} while (0)

    s16x8 aA[8], aB[8];

    // prologue: tile 0 -> slot 0 (B) + aA (A); full drain once
    STAGE_B(0, 0);
    AFRAG_LOAD(aA, 0);
    asm volatile("s_waitcnt vmcnt(0)" ::: "memory");
    __builtin_amdgcn_s_barrier();
    asm volatile("" ::: "memory");

#pragma unroll 1
    for (int it = 0; it < NT; it += 2) {
        TILE(it,     aA, aB);
        TILE(it + 1, aB, aA);
    }
#undef STAGE_B
#undef AFRAG_LOAD
#undef TILE

    // epilogue: per frag-column routing (nb 16-aligned -> wave-uniform nsel)
#pragma unroll
    for (int ni = 0; ni < 6; ++ni) {
        int nb   = n0 + wn * 96 + ni * 16;
        int nsel = nb >> 11;                // 0=q, 1=k, 2=v
        int nr   = nb & 2047;
        int h    = nr >> 7;
        int d    = (nr & 127) + r16;
        if (nsel < 2) {
            unsigned short* O = nsel ? Ok : Oq;
#pragma unroll
            for (int mi = 0; mi < 4; ++mi)
#pragma unroll
                for (int r = 0; r < 4; ++r) {
                    int m = m0 + wm * 64 + mi * 16 + q4 * 4 + r;
                    int b = m >> 11, l = m & 2047;
                    O[(((size_t)b * Hh + h) * Ll + l) * Hd + d] =
                        f2bf(acc[mi][ni][r]);
                }
        } else {
            // v: transposed store [b][h][d][l]; lane holds 4 consecutive l
#pragma unroll
            for (int mi = 0; mi < 4; ++mi) {
                int mb = m0 + wm * 64 + mi * 16 + q4 * 4;
                int b = mb >> 11, l = mb & 2047;
                ushort4 pk;
                pk.x = f2bf(acc[mi][ni][0]);
                pk.y = f2bf(acc[mi][ni][1]);
                pk.z = f2bf(acc[mi][ni][2]);
                pk.w = f2bf(acc[mi][ni][3]);
                *(ushort4*)&Ov[(((size_t)b * Hh + h) * Hd + d) * Ll + l] = pk;
            }
        }
    }
}

// ---------------------------------------------------------------------------
// Out-projection GEMM (proven r3 structure): C = A * W^T, fp32 store.
// BM=256 x BN=128, BK=64, 8 waves (4M x 2N), per-wave 64x64, 3 LDS slots,
// counted vmcnt(6), XOR swizzle.  Grid 16x16 = 256 blocks = 1 full round.
// ---------------------------------------------------------------------------
__global__ __launch_bounds__(512, 2)
void mfma_gemm_out(const unsigned short* __restrict__ A,
                   const unsigned short* __restrict__ W,
                   float* __restrict__ FO)
{
    constexpr int K  = 2048;
    constexpr int NT = K / 64;          // 32 K-tiles
    constexpr int SLOT_US = 24576;      // A 16384 + B 8192

    __shared__ unsigned short lds[3 * SLOT_US];   // 144 KiB

    const int t    = threadIdx.x;
    const int w    = t >> 6, lane = t & 63;
    const int wm   = w >> 1, wn = w & 1;
    const int m0   = blockIdx.y * 256, n0 = blockIdx.x * 128;
    const int r16  = lane & 15, q4 = lane >> 4;
    const int lxor = (r16 & 7) << 4;

    const int srow8 = lane >> 3;
    const int sgcol = (((lane & 7) ^ srow8) << 4);
    const char* Agb = (const char*)A;
    const char* Wgb = (const char*)W;

    f32x4 acc[4][4];
#pragma unroll
    for (int i = 0; i < 4; ++i)
#pragma unroll
        for (int j = 0; j < 4; ++j)
            acc[i][j] = (f32x4){0.f, 0.f, 0.f, 0.f};

    s16x8 af[4], bf[4];

#define STAGE_A(tt, sl, p) do {                                              \
    int ia_ = w * 4 + (p);                                                   \
    gld16(Agb + (size_t)(m0 + ia_ * 8 + srow8) * (K * 2) + (tt) * 128 + sgcol, \
          &lds[(sl) * SLOT_US + ia_ * 512]); } while (0)
#define STAGE_B(tt, sl, p) do {                                              \
    int ib_ = w * 2 + (p);                                                   \
    gld16(Wgb + (size_t)(n0 + ib_ * 8 + srow8) * (K * 2) + (tt) * 128 + sgcol, \
          &lds[(sl) * SLOT_US + 16384 + ib_ * 512]); } while (0)

#define LOAD_FRAGS(sl, ksub) do {                                            \
    const char* Ab_ = (const char*)&lds[(sl) * SLOT_US];                     \
    const char* Bb_ = (const char*)&lds[(sl) * SLOT_US + 16384];             \
    int cc_ = ((ksub) * 64 + q4 * 16) ^ lxor;                                \
    _Pragma("unroll") for (int mi = 0; mi < 4; ++mi)                         \
        af[mi] = *(const s16x8*)(Ab_ + (wm * 64 + mi * 16 + r16) * 128 + cc_); \
    _Pragma("unroll") for (int ni = 0; ni < 4; ++ni)                         \
        bf[ni] = *(const s16x8*)(Bb_ + (wn * 64 + ni * 16 + r16) * 128 + cc_); \
} while (0)

#define DO_MFMA() do {                                                       \
    __builtin_amdgcn_s_setprio(1);                                           \
    _Pragma("unroll") for (int mi = 0; mi < 4; ++mi)                         \
    _Pragma("unroll") for (int ni = 0; ni < 4; ++ni)                         \
        acc[mi][ni] = __builtin_amdgcn_mfma_f32_16x16x32_bf16(                \
            af[mi], bf[ni], acc[mi][ni], 0, 0, 0);                           \
    __builtin_amdgcn_s_setprio(0);                                           \
} while (0)

    STAGE_A(0, 0, 0); STAGE_A(0, 0, 1); STAGE_B(0, 0, 0);
    STAGE_A(0, 0, 2); STAGE_A(0, 0, 3); STAGE_B(0, 0, 1);
    STAGE_A(1, 1, 0); STAGE_A(1, 1, 1); STAGE_B(1, 1, 0);
    STAGE_A(1, 1, 2); STAGE_A(1, 1, 3); STAGE_B(1, 1, 1);
    asm volatile("s_waitcnt vmcnt(6)" ::: "memory");
    __builtin_amdgcn_s_barrier();
    asm volatile("" ::: "memory");

    int slot = 0;
    for (int tt = 0; tt < NT; ++tt) {
        int snx = slot + 2; if (snx >= 3) snx -= 3;
        const bool pf = (tt + 2 < NT);

        LOAD_FRAGS(slot, 0);
        if (pf) { STAGE_A(tt + 2, snx, 0); STAGE_A(tt + 2, snx, 1); STAGE_B(tt + 2, snx, 0); }
        asm volatile("" ::: "memory");
        __builtin_amdgcn_s_barrier();
        asm volatile("s_waitcnt lgkmcnt(0)" ::: "memory");
        DO_MFMA();
        asm volatile("" ::: "memory");
        __builtin_amdgcn_s_barrier();
        asm volatile("" ::: "memory");

        LOAD_FRAGS(slot, 1);
        if (pf) { STAGE_A(tt + 2, snx, 2); STAGE_A(tt + 2, snx, 3); STAGE_B(tt + 2, snx, 1); }
        asm volatile("" ::: "memory");
        __builtin_amdgcn_s_barrier();
        asm volatile("s_waitcnt lgkmcnt(0)" ::: "memory");
        DO_MFMA();
        if (pf)               asm volatile("s_waitcnt vmcnt(6)" ::: "memory");
        else if (tt + 1 < NT) asm volatile("s_waitcnt vmcnt(0)" ::: "memory");
        asm volatile("" ::: "memory");
        __builtin_amdgcn_s_barrier();
        asm volatile("" ::: "memory");

        slot = (slot == 2) ? 0 : slot + 1;
    }
#undef STAGE_A
#undef STAGE_B
#undef LOAD_FRAGS
#undef DO_MFMA

#pragma unroll
    for (int mi = 0; mi < 4; ++mi)
#pragma unroll
        for (int ni = 0; ni < 4; ++ni) {
            int n = n0 + wn * 64 + ni * 16 + r16;
#pragma unroll
            for (int r = 0; r < 4; ++r) {
                int m = m0 + wm * 64 + mi * 16 + q4 * 4 + r;
                FO[(size_t)m * Dd + n] = acc[mi][ni][r];
            }
        }
}

// ---------------------------------------------------------------------------
// RoPE in-place on bf16 q,k, vectorized short8 (G13).  16 threads/row,
// 16 rows/block; row lives in one wave.  q scaled by log2(e)/sqrt(128).
// grid: 8192 blocks (0..4095 = q, 4096..8191 = k).
// ---------------------------------------------------------------------------
__global__ __launch_bounds__(256)
void rope_bf16(unsigned short* __restrict__ q, unsigned short* __restrict__ k,
               const float* __restrict__ cosb, const float* __restrict__ sinb)
{
    const float QS = 0.1275175f;           // log2(e)/sqrt(128)
    const int t = threadIdx.x;
    int rblk = blockIdx.x;
    unsigned short* base;
    float sc;
    if (rblk < 4096) { base = q; sc = QS; }
    else             { base = k; sc = 1.0f; rblk -= 4096; }

    const int row = rblk * 16 + (t >> 4);  // [0, B*H*L)
    const int l   = row & (Ll - 1);
    const int d0  = (t & 15) * 8;
    unsigned short* xr = base + (size_t)row * Hd;

    s16x8 v0 = *(const s16x8*)(xr + d0);
    s16x8 vp = *(const s16x8*)(xr + (d0 ^ 64));
    const float* cp = cosb + (size_t)l * Hd + d0;
    const float* sp = sinb + (size_t)l * Hd + d0;
    float4 c0 = *(const float4*)cp,       c1 = *(const float4*)(cp + 4);
    float4 sa = *(const float4*)sp,       sb = *(const float4*)(sp + 4);
    const float cc[8] = {c0.x, c0.y, c0.z, c0.w, c1.x, c1.y, c1.z, c1.w};
    const float ss[8] = {sa.x, sa.y, sa.z, sa.w, sb.x, sb.y, sb.z, sb.w};
    const float sgn = (d0 < 64) ? -1.f : 1.f;

    s16x8 o;
#pragma unroll
    for (int j = 0; j < 8; ++j) {
        float a = bf2f((unsigned short)v0[j]);
        float p = bf2f((unsigned short)vp[j]);
        float res = fmaf(a, cc[j], sgn * p * ss[j]) * sc;
        o[j] = (short)f2bf(res);
    }
    asm volatile("" ::: "memory");         // loads (both halves) before store
    *(s16x8*)(xr + d0) = o;
}

// ---------------------------------------------------------------------------
// Flash attention (r3-proven): 32x32x16 bf16 MFMA, no-max softmax,
// double-buffered async gld_lds staging, XOR-swizzled linear LDS,
// one barrier per 64-key tile, setprio around MFMA clusters.
// LDS = 80 KiB -> 2 blocks/CU.
// ---------------------------------------------------------------------------
__global__ __launch_bounds__(256)
void flash_attn(const unsigned short* __restrict__ q,
                const unsigned short* __restrict__ k,
                const unsigned short* __restrict__ vT,
                unsigned short* __restrict__ ctx)
{
    __shared__ unsigned short Ks[2][64 * 128];   // [key][d] linear
    __shared__ unsigned short Vs[2][128 * 64];   // [d][key] linear
    __shared__ unsigned short Ps[4][32 * 64];    // per-wave [m][key]

    const int t = threadIdx.x;
    const int w = t >> 6, lane = t & 63;
    const int n32 = lane & 31, half = lane >> 5;
    const int bh = blockIdx.x >> 4;              // 16 q-tiles of 128 per (b,h)
    const int l0 = (blockIdx.x & 15) * 128;

    const unsigned short* qb = q  + ((size_t)bh * Ll + l0 + w * 32) * Hd;
    const unsigned short* kb = k  + (size_t)bh * Ll * Hd;
    const unsigned short* vb = vT + (size_t)bh * Hd * Ll;

    const int k_r = lane >> 4, k_u = lane & 15;  // K: 4 rows x 256 B per instr
    const int v_r = lane >> 3, v_u = lane & 7;   // V: 8 rows x 128 B per instr

#define STAGE(J0, bsel) do {                                                  \
    _Pragma("unroll") for (int p = 0; p < 4; ++p) {                           \
        int j_ = w * 4 + p;                                                   \
        int row_ = j_ * 4 + k_r;                                              \
        gld16(kb + (size_t)((J0) + row_) * Hd + ((k_u ^ (row_ & 7)) * 8),     \
              &Ks[bsel][j_ * 512]);                                           \
    }                                                                         \
    _Pragma("unroll") for (int p = 0; p < 4; ++p) {                           \
        int j_ = w * 4 + p;                                                   \
        int row_ = j_ * 8 + v_r;                                              \
        gld16(vb + (size_t)row_ * Ll + (J0) + ((v_u ^ (row_ & 7)) * 8),       \
              &Vs[bsel][j_ * 512]);                                           \
    }                                                                         \
} while (0)

    s16x8 qf[8];
#pragma unroll
    for (int ks = 0; ks < 8; ++ks)
        qf[ks] = *(const s16x8*)(qb + (size_t)n32 * Hd + ks * 16 + half * 8);

    f32x16 o[4];
    float lacc[16];
#pragma unroll
    for (int nt = 0; nt < 4; ++nt)
#pragma unroll
        for (int r = 0; r < 16; ++r) o[nt][r] = 0.f;
#pragma unroll
    for (int r = 0; r < 16; ++r) lacc[r] = 0.f;

    unsigned short* Pw = Ps[w];
    const int psw = (n32 & 7) << 3;              // read-side swizzle (row n32)

    STAGE(0, 0);
    __syncthreads();

    int buf = 0;
    for (int j0 = 0; j0 < Ll; j0 += 64) {
        if (j0 + 64 < Ll) STAGE(j0 + 64, buf ^ 1);   // in flight across compute

        f32x16 s0, s1;
#pragma unroll
        for (int r = 0; r < 16; ++r) { s0[r] = 0.f; s1[r] = 0.f; }
        __builtin_amdgcn_s_setprio(1);
#pragma unroll
        for (int ks = 0; ks < 8; ++ks) {
            int kc = (ks * 16 + half * 8) ^ psw;
            s16x8 b0 = *(const s16x8*)&Ks[buf][n32 * 128 + kc];
            s16x8 b1 = *(const s16x8*)&Ks[buf][(32 + n32) * 128 + kc];
            s0 = __builtin_amdgcn_mfma_f32_32x32x16_bf16(qf[ks], b0, s0, 0, 0, 0);
            s1 = __builtin_amdgcn_mfma_f32_32x32x16_bf16(qf[ks], b1, s1, 0, 0, 0);
        }
        __builtin_amdgcn_s_setprio(0);

#pragma unroll
        for (int r = 0; r < 16; ++r) {
            int mrow = (r & 3) + 8 * (r >> 2) + 4 * half;
            int sw = (mrow & 7) << 3;
            float p0 = fast_exp2(s0[r]);
            float p1 = fast_exp2(s1[r]);
            lacc[r] += p0 + p1;
            union { float f; unsigned u; } u0, u1;
            u0.f = p0; u1.f = p1;
            Pw[mrow * 64 + (n32 ^ sw)]        = (unsigned short)((u0.u + 0x8000u) >> 16);
            Pw[mrow * 64 + ((32 + n32) ^ sw)] = (unsigned short)((u1.u + 0x8000u) >> 16);
        }

        __builtin_amdgcn_s_setprio(1);
#pragma unroll
        for (int kst = 0; kst < 4; ++kst) {
            int cc = (kst * 16 + half * 8) ^ psw;
            s16x8 pf2 = *(const s16x8*)&Pw[n32 * 64 + cc];
#pragma unroll
            for (int nt = 0; nt < 4; ++nt) {
                s16x8 vf = *(const s16x8*)&Vs[buf][(nt * 32 + n32) * 64 + cc];
                o[nt] = __builtin_amdgcn_mfma_f32_32x32x16_bf16(pf2, vf, o[nt], 0, 0, 0);
            }
        }
        __builtin_amdgcn_s_setprio(0);

        __syncthreads();     // drains vmcnt(0): next tile staged; buffer swap
        buf ^= 1;
    }
#undef STAGE

    float linv[16];
#pragma unroll
    for (int r = 0; r < 16; ++r) {
        float s = lacc[r];
        s += __shfl_xor(s, 1, 64);
        s += __shfl_xor(s, 2, 64);
        s += __shfl_xor(s, 4, 64);
        s += __shfl_xor(s, 8, 64);
        s += __shfl_xor(s, 16, 64);
        linv[r] = 1.0f / s;
    }

    const int b = bh >> 4, h = bh & 15;
#pragma unroll
    for (int nt = 0; nt < 4; ++nt)
#pragma unroll
        for (int r = 0; r < 16; ++r) {
            int mrow = (r & 3) + 8 * (r >> 2) + 4 * half;
            int lq = l0 + w * 32 + mrow;
            ctx[((size_t)(b * Ll + lq)) * Dd + h * Hd + nt * 32 + n32] =
                f2bf(o[nt][r] * linv[r]);
        }
}

// ---------------------------------------------------------------------------
// Workspace (96 MB): [Xb 16M][Wq 8M][Wk 8M][Wv 8M][Wo 8M][q 16M][k 16M][vT 16M]
// Wq/Wk/Wv contiguous -> fused QKV GEMM reads them as one [6144][2048] W.
// ctx reuses the Xb slot (X dead after QKV GEMM).
// ---------------------------------------------------------------------------
extern "C" void kernel_launch(void* const* d_in, const int* in_sizes, int n_in,
                              void* d_out, int out_size, void* d_ws, size_t ws_size,
                              hipStream_t stream)
{
    const float* hs   = (const float*)d_in[0];
    const float* cosb = (const float*)d_in[1];
    const float* sinb = (const float*)d_in[2];
    const float* wq   = (const float*)d_in[3];
    const float* wk   = (const float*)d_in[4];
    const float* wv   = (const float*)d_in[5];
    const float* wo   = (const float*)d_in[6];
    float* out = (float*)d_out;

    char* ws = (char*)d_ws;
    unsigned short* Xb  = (unsigned short*)(ws);
    unsigned short* Wqb = (unsigned short*)(ws + (16ull << 20));
    unsigned short* Wkb = (unsigned short*)(ws + (24ull << 20));
    unsigned short* Wvb = (unsigned short*)(ws + (32ull << 20));
    unsigned short* Wob = (unsigned short*)(ws + (40ull << 20));
    unsigned short* qb  = (unsigned short*)(ws + (48ull << 20));
    unsigned short* kb  = (unsigned short*)(ws + (64ull << 20));
    unsigned short* vTb = (unsigned short*)(ws + (80ull << 20));
    unsigned short* ctx = Xb;

    // fp32 -> bf16, all tensors, one launch (24576 blocks)
    f2bf_all<<<dim3(24576), dim3(256), 0, stream>>>(
        hs, wq, wk, wv, wo, Xb, Wqb, Wkb, Wvb, Wob);

    // Fused QKV projection: A [4096x2048] x W [6144x2048]^T
    // BM=128 x BN=192, A-direct-from-global, 3 blocks/CU; grid 32x32 = 1024
    mfma_gemm_qkv<<<dim3(6144 / 192, M / 128), dim3(256), 0, stream>>>(
        Xb, Wqb, qb, kb, vTb);

    // RoPE: 16 rows/block, vectorized; blocks 0..4095 = q, 4096..8191 = k
    rope_bf16<<<dim3(2 * (Bb * Hh * Ll) / 16), dim3(256), 0, stream>>>(
        qb, kb, cosb, sinb);

    // Flash attention: 128 q-rows/block, 512 blocks (exactly 2/CU)
    flash_attn<<<dim3(Bb * Hh * (Ll / 128)), dim3(256), 0, stream>>>(qb, kb, vTb, ctx);

    // Output projection -> fp32 d_out (256 blocks = 1 full round)
    mfma_gemm_out<<<dim3(Dd / 128, M / 256), dim3(512), 0, stream>>>(
        ctx, Wob, out);
}

// Round 8
// 536.427 us; speedup vs baseline: 1.7889x; 1.7889x over previous
//
#include <hip/hip_runtime.h>

// Problem constants
constexpr int Bb = 2;
constexpr int Ll = 2048;
constexpr int Dd = 2048;
constexpr int Hh = 16;
constexpr int Hd = 128;
constexpr int M  = Bb * Ll;   // 4096

typedef __attribute__((ext_vector_type(8)))  short s16x8;   // 8 bf16 (4 VGPRs)
typedef __attribute__((ext_vector_type(4)))  float f32x4;   // 16x16 C/D
typedef __attribute__((ext_vector_type(16))) float f32x16;  // 32x32 C/D

__device__ __forceinline__ unsigned short f2bf(float f) {
    union { float f; unsigned u; } v; v.f = f;
    unsigned r = v.u + 0x7fffu + ((v.u >> 16) & 1u);   // RNE
    return (unsigned short)(r >> 16);
}
__device__ __forceinline__ float bf2f(unsigned short b) {
    union { unsigned u; float f; } v; v.u = ((unsigned)b) << 16;
    return v.f;
}
__device__ __forceinline__ float fast_exp2(float x) {
#if __has_builtin(__builtin_amdgcn_exp2f)
    return __builtin_amdgcn_exp2f(x);
#else
    return exp2f(x);
#endif
}

// async global->LDS, 16 B per lane; lds dest = wave-uniform base + lane*16
__device__ __forceinline__ void gld16(const void* g, void* l) {
#if __has_builtin(__builtin_amdgcn_global_load_lds)
    __builtin_amdgcn_global_load_lds(
        (const __attribute__((address_space(1))) unsigned int*)g,
        (__attribute__((address_space(3))) unsigned int*)l, 16, 0, 0);
#else
    int lane = threadIdx.x & 63;
    ((int4*)l)[lane] = ((const int4*)g)[0];
#endif
}

// ---------------------------------------------------------------------------
// fp32 -> bf16 conversion, all 5 tensors in ONE launch.
// Segments (exact 1024-elem blocks): X 8192 | wq 4096 | wk 4096 | wv 4096 |
// wo 4096 = 24576 blocks total.
// ---------------------------------------------------------------------------
__global__ __launch_bounds__(256)
void f2bf_all(const float* __restrict__ x,  const float* __restrict__ wq,
              const float* __restrict__ wk, const float* __restrict__ wv,
              const float* __restrict__ wo,
              unsigned short* __restrict__ Xb,  unsigned short* __restrict__ Wqb,
              unsigned short* __restrict__ Wkb, unsigned short* __restrict__ Wvb,
              unsigned short* __restrict__ Wob)
{
    int bid = blockIdx.x;
    const float* in; unsigned short* out; int off;
    if      (bid <  8192) { in = x;  out = Xb;  off = bid; }
    else if (bid < 12288) { in = wq; out = Wqb; off = bid - 8192; }
    else if (bid < 16384) { in = wk; out = Wkb; off = bid - 12288; }
    else if (bid < 20480) { in = wv; out = Wvb; off = bid - 16384; }
    else                  { in = wo; out = Wob; off = bid - 20480; }
    int i = (off * 256 + threadIdx.x) * 4;
    float4 v = *(const float4*)(in + i);
    ushort4 o;
    o.x = f2bf(v.x); o.y = f2bf(v.y); o.z = f2bf(v.z); o.w = f2bf(v.w);
    *(ushort4*)(out + i) = o;
}

// ---------------------------------------------------------------------------
// Fused QKV GEMM, A-direct-from-global (LDS-traffic cut):
// C = A * Wall^T.  A [4096][2048] bf16, Wall [6144][2048] (wq;wk;wv stacked).
// BM=128 x BN=192, BK=64, 256 threads = 4 waves (2M x 2N), per-wave 64x96.
// A-frags load STRAIGHT from global into registers (row=r16, kchunk=q4,
// 16B/lane) -> removes 8/20 ds_reads and 16/40 KiB LDS writes per tile;
// A flows via L1/L2 (overlaps the LDS pipe).  B stays LDS-staged (gld_lds,
// XOR-swizzled both-sides).  LDS = 2 x 24 KiB = 48 KiB.
// R7 post-mortem: __launch_bounds__(256,3) capped VGPR ~170 < ~210 live ->
// accumulator spill (WRITE_SIZE 1.5 GB, VGPR_Count 84).  Fix: bound (256,2)
// -> VGPR cap 256, no spill, 2 blocks/CU (VGPR-limited; LDS would allow 3).
// Per tile: issue B-stage(t+1) FIRST, then 8 A-frag loads(t+1) into the
// alternate named reg buffer (2-tile unroll, static idx); 48 MFMA; counted
// vmcnt(8) (drains the 6 oldest = B stages; A-prefetch loads stay in
// flight, compiler auto-waitcnt covers their first use); one barrier.
// Grid 32x32 = 1024 blocks.
// ---------------------------------------------------------------------------
__global__ __launch_bounds__(256, 2)
void mfma_gemm_qkv(const unsigned short* __restrict__ A,
                   const unsigned short* __restrict__ Wall,
                   unsigned short* __restrict__ Oq,
                   unsigned short* __restrict__ Ok,
                   unsigned short* __restrict__ Ov)
{
    constexpr int K  = 2048;
    constexpr int NT = K / 64;          // 32 K-tiles
    constexpr int BM = 128, BN = 192;
    constexpr int SLOT_US = BN * 64;    // 12288 ushorts = 24 KiB (B only)

    __shared__ unsigned short lds[2 * SLOT_US];   // 48 KiB

    const int t    = threadIdx.x;
    const int w    = t >> 6, lane = t & 63;
    const int wm   = w >> 1, wn = w & 1;          // 2M x 2N
    const int m0   = blockIdx.y * BM, n0 = blockIdx.x * BN;
    const int r16  = lane & 15, q4 = lane >> 4;
    const int lxor = (r16 & 7) << 4;              // B read-side swizzle XOR

    // B staging lane constants: 8 lanes per 128B row; swizzled source column
    const int srow8 = lane >> 3;
    const int sgcol = (((lane & 7) ^ srow8) << 4);
    const char* Agb = (const char*)A;
    const char* Wgb = (const char*)Wall;

    const int c0 = (q4 * 16) ^ lxor;              // ksub0 byte col (swizzled)
    const int c1 = (64 + q4 * 16) ^ lxor;         // ksub1

    f32x4 acc[4][6];
#pragma unroll
    for (int i = 0; i < 4; ++i)
#pragma unroll
        for (int j = 0; j < 6; ++j)
            acc[i][j] = (f32x4){0.f, 0.f, 0.f, 0.f};

// B stage: 24 gld16/block (ib=w*6+p), 6 per wave
#define STAGE_B(tt, sl) do {                                                 \
    _Pragma("unroll") for (int p = 0; p < 6; ++p) {                          \
        int ib_ = w * 6 + p;                                                 \
        gld16(Wgb + (size_t)(n0 + ib_ * 8 + srow8) * (K * 2) + (tt) * 128 + sgcol, \
              &lds[(sl) * SLOT_US + ib_ * 512]);                             \
    } } while (0)

// A frags direct from global: dst[0..3]=ks0, dst[4..7]=ks1 (8 x 16B loads)
#define AFRAG_LOAD(dst, tt) do {                                             \
    _Pragma("unroll") for (int mi = 0; mi < 4; ++mi) {                       \
        const char* ap_ = Agb + (size_t)(m0 + wm * 64 + mi * 16 + r16) * (K * 2) \
                          + (tt) * 128 + q4 * 16;                            \
        dst[mi]     = *(const s16x8*)(ap_);                                  \
        dst[4 + mi] = *(const s16x8*)(ap_ + 64);                             \
    } } while (0)

// one K-tile: prefetch t+1 (B->LDS slot^1, A->aN regs), compute from aC+slot
#define TILE(tt, aC, aN) do {                                                \
    const int sl_ = (tt) & 1;                                                \
    if ((tt) + 1 < NT) {                                                     \
        STAGE_B((tt) + 1, sl_ ^ 1);                                          \
        asm volatile("" ::: "memory");      /* pin issue order: B before A */ \
        AFRAG_LOAD(aN, (tt) + 1);                                            \
        asm volatile("" ::: "memory");                                       \
    }                                                                        \
    const char* Bp_ = (const char*)&lds[sl_ * SLOT_US];                      \
    s16x8 bf_[6];                                                            \
    _Pragma("unroll") for (int ni = 0; ni < 6; ++ni)                         \
        bf_[ni] = *(const s16x8*)(Bp_ + (wn * 96 + ni * 16 + r16) * 128 + c0); \
    __builtin_amdgcn_s_setprio(1);                                           \
    _Pragma("unroll") for (int mi = 0; mi < 4; ++mi)                         \
    _Pragma("unroll") for (int ni = 0; ni < 6; ++ni)                         \
        acc[mi][ni] = __builtin_amdgcn_mfma_f32_16x16x32_bf16(                \
            aC[mi], bf_[ni], acc[mi][ni], 0, 0, 0);                          \
    __builtin_amdgcn_s_setprio(0);                                           \
    _Pragma("unroll") for (int ni = 0; ni < 6; ++ni)                         \
        bf_[ni] = *(const s16x8*)(Bp_ + (wn * 96 + ni * 16 + r16) * 128 + c1); \
    __builtin_amdgcn_s_setprio(1);                                           \
    _Pragma("unroll") for (int mi = 0; mi < 4; ++mi)                         \
    _Pragma("unroll") for (int ni = 0; ni < 6; ++ni)                         \
        acc[mi][ni] = __builtin_amdgcn_mfma_f32_16x16x32_bf16(                \
            aC[4 + mi], bf_[ni], acc[mi][ni], 0, 0, 0);                      \
    __builtin_amdgcn_s_setprio(0);                                           \
    if ((tt) + 1 < NT) {                                                     \
        asm volatile("s_waitcnt vmcnt(8)" ::: "memory"); /* 6 oldest = B */  \
        __builtin_amdgcn_s_barrier();                                        \
        asm volatile("" ::: "memory");                                       \
    }                                                                        \
} while (0)

    s16x8 aA[8], aB[8];

    // prologue: tile 0 -> slot 0 (B) + aA (A); full drain once
    STAGE_B(0, 0);
    AFRAG_LOAD(aA, 0);
    asm volatile("s_waitcnt vmcnt(0)" ::: "memory");
    __builtin_amdgcn_s_barrier();
    asm volatile("" ::: "memory");

#pragma unroll 1
    for (int it = 0; it < NT; it += 2) {
        TILE(it,     aA, aB);
        TILE(it + 1, aB, aA);
    }
#undef STAGE_B
#undef AFRAG_LOAD
#undef TILE

    // epilogue: per frag-column routing (nb 16-aligned -> wave-uniform nsel)
#pragma unroll
    for (int ni = 0; ni < 6; ++ni) {
        int nb   = n0 + wn * 96 + ni * 16;
        int nsel = nb >> 11;                // 0=q, 1=k, 2=v
        int nr   = nb & 2047;
        int h    = nr >> 7;
        int d    = (nr & 127) + r16;
        if (nsel < 2) {
            unsigned short* O = nsel ? Ok : Oq;
#pragma unroll
            for (int mi = 0; mi < 4; ++mi)
#pragma unroll
                for (int r = 0; r < 4; ++r) {
                    int m = m0 + wm * 64 + mi * 16 + q4 * 4 + r;
                    int b = m >> 11, l = m & 2047;
                    O[(((size_t)b * Hh + h) * Ll + l) * Hd + d] =
                        f2bf(acc[mi][ni][r]);
                }
        } else {
            // v: transposed store [b][h][d][l]; lane holds 4 consecutive l
#pragma unroll
            for (int mi = 0; mi < 4; ++mi) {
                int mb = m0 + wm * 64 + mi * 16 + q4 * 4;
                int b = mb >> 11, l = mb & 2047;
                ushort4 pk;
                pk.x = f2bf(acc[mi][ni][0]);
                pk.y = f2bf(acc[mi][ni][1]);
                pk.z = f2bf(acc[mi][ni][2]);
                pk.w = f2bf(acc[mi][ni][3]);
                *(ushort4*)&Ov[(((size_t)b * Hh + h) * Hd + d) * Ll + l] = pk;
            }
        }
    }
}

// ---------------------------------------------------------------------------
// Out-projection GEMM (proven r3 structure): C = A * W^T, fp32 store.
// BM=256 x BN=128, BK=64, 8 waves (4M x 2N), per-wave 64x64, 3 LDS slots,
// counted vmcnt(6), XOR swizzle.  Grid 16x16 = 256 blocks = 1 full round.
// ---------------------------------------------------------------------------
__global__ __launch_bounds__(512, 2)
void mfma_gemm_out(const unsigned short* __restrict__ A,
                   const unsigned short* __restrict__ W,
                   float* __restrict__ FO)
{
    constexpr int K  = 2048;
    constexpr int NT = K / 64;          // 32 K-tiles
    constexpr int SLOT_US = 24576;      // A 16384 + B 8192

    __shared__ unsigned short lds[3 * SLOT_US];   // 144 KiB

    const int t    = threadIdx.x;
    const int w    = t >> 6, lane = t & 63;
    const int wm   = w >> 1, wn = w & 1;
    const int m0   = blockIdx.y * 256, n0 = blockIdx.x * 128;
    const int r16  = lane & 15, q4 = lane >> 4;
    const int lxor = (r16 & 7) << 4;

    const int srow8 = lane >> 3;
    const int sgcol = (((lane & 7) ^ srow8) << 4);
    const char* Agb = (const char*)A;
    const char* Wgb = (const char*)W;

    f32x4 acc[4][4];
#pragma unroll
    for (int i = 0; i < 4; ++i)
#pragma unroll
        for (int j = 0; j < 4; ++j)
            acc[i][j] = (f32x4){0.f, 0.f, 0.f, 0.f};

    s16x8 af[4], bf[4];

#define STAGE_A(tt, sl, p) do {                                              \
    int ia_ = w * 4 + (p);                                                   \
    gld16(Agb + (size_t)(m0 + ia_ * 8 + srow8) * (K * 2) + (tt) * 128 + sgcol, \
          &lds[(sl) * SLOT_US + ia_ * 512]); } while (0)
#define STAGE_B(tt, sl, p) do {                                              \
    int ib_ = w * 2 + (p);                                                   \
    gld16(Wgb + (size_t)(n0 + ib_ * 8 + srow8) * (K * 2) + (tt) * 128 + sgcol, \
          &lds[(sl) * SLOT_US + 16384 + ib_ * 512]); } while (0)

#define LOAD_FRAGS(sl, ksub) do {                                            \
    const char* Ab_ = (const char*)&lds[(sl) * SLOT_US];                     \
    const char* Bb_ = (const char*)&lds[(sl) * SLOT_US + 16384];             \
    int cc_ = ((ksub) * 64 + q4 * 16) ^ lxor;                                \
    _Pragma("unroll") for (int mi = 0; mi < 4; ++mi)                         \
        af[mi] = *(const s16x8*)(Ab_ + (wm * 64 + mi * 16 + r16) * 128 + cc_); \
    _Pragma("unroll") for (int ni = 0; ni < 4; ++ni)                         \
        bf[ni] = *(const s16x8*)(Bb_ + (wn * 64 + ni * 16 + r16) * 128 + cc_); \
} while (0)

#define DO_MFMA() do {                                                       \
    __builtin_amdgcn_s_setprio(1);                                           \
    _Pragma("unroll") for (int mi = 0; mi < 4; ++mi)                         \
    _Pragma("unroll") for (int ni = 0; ni < 4; ++ni)                         \
        acc[mi][ni] = __builtin_amdgcn_mfma_f32_16x16x32_bf16(                \
            af[mi], bf[ni], acc[mi][ni], 0, 0, 0);                           \
    __builtin_amdgcn_s_setprio(0);                                           \
} while (0)

    STAGE_A(0, 0, 0); STAGE_A(0, 0, 1); STAGE_B(0, 0, 0);
    STAGE_A(0, 0, 2); STAGE_A(0, 0, 3); STAGE_B(0, 0, 1);
    STAGE_A(1, 1, 0); STAGE_A(1, 1, 1); STAGE_B(1, 1, 0);
    STAGE_A(1, 1, 2); STAGE_A(1, 1, 3); STAGE_B(1, 1, 1);
    asm volatile("s_waitcnt vmcnt(6)" ::: "memory");
    __builtin_amdgcn_s_barrier();
    asm volatile("" ::: "memory");

    int slot = 0;
    for (int tt = 0; tt < NT; ++tt) {
        int snx = slot + 2; if (snx >= 3) snx -= 3;
        const bool pf = (tt + 2 < NT);

        LOAD_FRAGS(slot, 0);
        if (pf) { STAGE_A(tt + 2, snx, 0); STAGE_A(tt + 2, snx, 1); STAGE_B(tt + 2, snx, 0); }
        asm volatile("" ::: "memory");
        __builtin_amdgcn_s_barrier();
        asm volatile("s_waitcnt lgkmcnt(0)" ::: "memory");
        DO_MFMA();
        asm volatile("" ::: "memory");
        __builtin_amdgcn_s_barrier();
        asm volatile("" ::: "memory");

        LOAD_FRAGS(slot, 1);
        if (pf) { STAGE_A(tt + 2, snx, 2); STAGE_A(tt + 2, snx, 3); STAGE_B(tt + 2, snx, 1); }
        asm volatile("" ::: "memory");
        __builtin_amdgcn_s_barrier();
        asm volatile("s_waitcnt lgkmcnt(0)" ::: "memory");
        DO_MFMA();
        if (pf)               asm volatile("s_waitcnt vmcnt(6)" ::: "memory");
        else if (tt + 1 < NT) asm volatile("s_waitcnt vmcnt(0)" ::: "memory");
        asm volatile("" ::: "memory");
        __builtin_amdgcn_s_barrier();
        asm volatile("" ::: "memory");

        slot = (slot == 2) ? 0 : slot + 1;
    }
#undef STAGE_A
#undef STAGE_B
#undef LOAD_FRAGS
#undef DO_MFMA

#pragma unroll
    for (int mi = 0; mi < 4; ++mi)
#pragma unroll
        for (int ni = 0; ni < 4; ++ni) {
            int n = n0 + wn * 64 + ni * 16 + r16;
#pragma unroll
            for (int r = 0; r < 4; ++r) {
                int m = m0 + wm * 64 + mi * 16 + q4 * 4 + r;
                FO[(size_t)m * Dd + n] = acc[mi][ni][r];
            }
        }
}

// ---------------------------------------------------------------------------
// RoPE in-place on bf16 q,k, vectorized short8 (G13).  16 threads/row,
// 16 rows/block; row lives in one wave.  q scaled by log2(e)/sqrt(128).
// grid: 8192 blocks (0..4095 = q, 4096..8191 = k).
// ---------------------------------------------------------------------------
__global__ __launch_bounds__(256)
void rope_bf16(unsigned short* __restrict__ q, unsigned short* __restrict__ k,
               const float* __restrict__ cosb, const float* __restrict__ sinb)
{
    const float QS = 0.1275175f;           // log2(e)/sqrt(128)
    const int t = threadIdx.x;
    int rblk = blockIdx.x;
    unsigned short* base;
    float sc;
    if (rblk < 4096) { base = q; sc = QS; }
    else             { base = k; sc = 1.0f; rblk -= 4096; }

    const int row = rblk * 16 + (t >> 4);  // [0, B*H*L)
    const int l   = row & (Ll - 1);
    const int d0  = (t & 15) * 8;
    unsigned short* xr = base + (size_t)row * Hd;

    s16x8 v0 = *(const s16x8*)(xr + d0);
    s16x8 vp = *(const s16x8*)(xr + (d0 ^ 64));
    const float* cp = cosb + (size_t)l * Hd + d0;
    const float* sp = sinb + (size_t)l * Hd + d0;
    float4 c0 = *(const float4*)cp,       c1 = *(const float4*)(cp + 4);
    float4 sa = *(const float4*)sp,       sb = *(const float4*)(sp + 4);
    const float cc[8] = {c0.x, c0.y, c0.z, c0.w, c1.x, c1.y, c1.z, c1.w};
    const float ss[8] = {sa.x, sa.y, sa.z, sa.w, sb.x, sb.y, sb.z, sb.w};
    const float sgn = (d0 < 64) ? -1.f : 1.f;

    s16x8 o;
#pragma unroll
    for (int j = 0; j < 8; ++j) {
        float a = bf2f((unsigned short)v0[j]);
        float p = bf2f((unsigned short)vp[j]);
        float res = fmaf(a, cc[j], sgn * p * ss[j]) * sc;
        o[j] = (short)f2bf(res);
    }
    asm volatile("" ::: "memory");         // loads (both halves) before store
    *(s16x8*)(xr + d0) = o;
}

// ---------------------------------------------------------------------------
// Flash attention (r3-proven): 32x32x16 bf16 MFMA, no-max softmax,
// double-buffered async gld_lds staging, XOR-swizzled linear LDS,
// one barrier per 64-key tile, setprio around MFMA clusters.
// LDS = 80 KiB -> 2 blocks/CU.
// ---------------------------------------------------------------------------
__global__ __launch_bounds__(256)
void flash_attn(const unsigned short* __restrict__ q,
                const unsigned short* __restrict__ k,
                const unsigned short* __restrict__ vT,
                unsigned short* __restrict__ ctx)
{
    __shared__ unsigned short Ks[2][64 * 128];   // [key][d] linear
    __shared__ unsigned short Vs[2][128 * 64];   // [d][key] linear
    __shared__ unsigned short Ps[4][32 * 64];    // per-wave [m][key]

    const int t = threadIdx.x;
    const int w = t >> 6, lane = t & 63;
    const int n32 = lane & 31, half = lane >> 5;
    const int bh = blockIdx.x >> 4;              // 16 q-tiles of 128 per (b,h)
    const int l0 = (blockIdx.x & 15) * 128;

    const unsigned short* qb = q  + ((size_t)bh * Ll + l0 + w * 32) * Hd;
    const unsigned short* kb = k  + (size_t)bh * Ll * Hd;
    const unsigned short* vb = vT + (size_t)bh * Hd * Ll;

    const int k_r = lane >> 4, k_u = lane & 15;  // K: 4 rows x 256 B per instr
    const int v_r = lane >> 3, v_u = lane & 7;   // V: 8 rows x 128 B per instr

#define STAGE(J0, bsel) do {                                                  \
    _Pragma("unroll") for (int p = 0; p < 4; ++p) {                           \
        int j_ = w * 4 + p;                                                   \
        int row_ = j_ * 4 + k_r;                                              \
        gld16(kb + (size_t)((J0) + row_) * Hd + ((k_u ^ (row_ & 7)) * 8),     \
              &Ks[bsel][j_ * 512]);                                           \
    }                                                                         \
    _Pragma("unroll") for (int p = 0; p < 4; ++p) {                           \
        int j_ = w * 4 + p;                                                   \
        int row_ = j_ * 8 + v_r;                                              \
        gld16(vb + (size_t)row_ * Ll + (J0) + ((v_u ^ (row_ & 7)) * 8),       \
              &Vs[bsel][j_ * 512]);                                           \
    }                                                                         \
} while (0)

    s16x8 qf[8];
#pragma unroll
    for (int ks = 0; ks < 8; ++ks)
        qf[ks] = *(const s16x8*)(qb + (size_t)n32 * Hd + ks * 16 + half * 8);

    f32x16 o[4];
    float lacc[16];
#pragma unroll
    for (int nt = 0; nt < 4; ++nt)
#pragma unroll
        for (int r = 0; r < 16; ++r) o[nt][r] = 0.f;
#pragma unroll
    for (int r = 0; r < 16; ++r) lacc[r] = 0.f;

    unsigned short* Pw = Ps[w];
    const int psw = (n32 & 7) << 3;              // read-side swizzle (row n32)

    STAGE(0, 0);
    __syncthreads();

    int buf = 0;
    for (int j0 = 0; j0 < Ll; j0 += 64) {
        if (j0 + 64 < Ll) STAGE(j0 + 64, buf ^ 1);   // in flight across compute

        f32x16 s0, s1;
#pragma unroll
        for (int r = 0; r < 16; ++r) { s0[r] = 0.f; s1[r] = 0.f; }
        __builtin_amdgcn_s_setprio(1);
#pragma unroll
        for (int ks = 0; ks < 8; ++ks) {
            int kc = (ks * 16 + half * 8) ^ psw;
            s16x8 b0 = *(const s16x8*)&Ks[buf][n32 * 128 + kc];
            s16x8 b1 = *(const s16x8*)&Ks[buf][(32 + n32) * 128 + kc];
            s0 = __builtin_amdgcn_mfma_f32_32x32x16_bf16(qf[ks], b0, s0, 0, 0, 0);
            s1 = __builtin_amdgcn_mfma_f32_32x32x16_bf16(qf[ks], b1, s1, 0, 0, 0);
        }
        __builtin_amdgcn_s_setprio(0);

#pragma unroll
        for (int r = 0; r < 16; ++r) {
            int mrow = (r & 3) + 8 * (r >> 2) + 4 * half;
            int sw = (mrow & 7) << 3;
            float p0 = fast_exp2(s0[r]);
            float p1 = fast_exp2(s1[r]);
            lacc[r] += p0 + p1;
            union { float f; unsigned u; } u0, u1;
            u0.f = p0; u1.f = p1;
            Pw[mrow * 64 + (n32 ^ sw)]        = (unsigned short)((u0.u + 0x8000u) >> 16);
            Pw[mrow * 64 + ((32 + n32) ^ sw)] = (unsigned short)((u1.u + 0x8000u) >> 16);
        }

        __builtin_amdgcn_s_setprio(1);
#pragma unroll
        for (int kst = 0; kst < 4; ++kst) {
            int cc = (kst * 16 + half * 8) ^ psw;
            s16x8 pf2 = *(const s16x8*)&Pw[n32 * 64 + cc];
#pragma unroll
            for (int nt = 0; nt < 4; ++nt) {
                s16x8 vf = *(const s16x8*)&Vs[buf][(nt * 32 + n32) * 64 + cc];
                o[nt] = __builtin_amdgcn_mfma_f32_32x32x16_bf16(pf2, vf, o[nt], 0, 0, 0);
            }
        }
        __builtin_amdgcn_s_setprio(0);

        __syncthreads();     // drains vmcnt(0): next tile staged; buffer swap
        buf ^= 1;
    }
#undef STAGE

    float linv[16];
#pragma unroll
    for (int r = 0; r < 16; ++r) {
        float s = lacc[r];
        s += __shfl_xor(s, 1, 64);
        s += __shfl_xor(s, 2, 64);
        s += __shfl_xor(s, 4, 64);
        s += __shfl_xor(s, 8, 64);
        s += __shfl_xor(s, 16, 64);
        linv[r] = 1.0f / s;
    }

    const int b = bh >> 4, h = bh & 15;
#pragma unroll
    for (int nt = 0; nt < 4; ++nt)
#pragma unroll
        for (int r = 0; r < 16; ++r) {
            int mrow = (r & 3) + 8 * (r >> 2) + 4 * half;
            int lq = l0 + w * 32 + mrow;
            ctx[((size_t)(b * Ll + lq)) * Dd + h * Hd + nt * 32 + n32] =
                f2bf(o[nt][r] * linv[r]);
        }
}

// ---------------------------------------------------------------------------
// Workspace (96 MB): [Xb 16M][Wq 8M][Wk 8M][Wv 8M][Wo 8M][q 16M][k 16M][vT 16M]
// Wq/Wk/Wv contiguous -> fused QKV GEMM reads them as one [6144][2048] W.
// ctx reuses the Xb slot (X dead after QKV GEMM).
// ---------------------------------------------------------------------------
extern "C" void kernel_launch(void* const* d_in, const int* in_sizes, int n_in,
                              void* d_out, int out_size, void* d_ws, size_t ws_size,
                              hipStream_t stream)
{
    const float* hs   = (const float*)d_in[0];
    const float* cosb = (const float*)d_in[1];
    const float* sinb = (const float*)d_in[2];
    const float* wq   = (const float*)d_in[3];
    const float* wk   = (const float*)d_in[4];
    const float* wv   = (const float*)d_in[5];
    const float* wo   = (const float*)d_in[6];
    float* out = (float*)d_out;

    char* ws = (char*)d_ws;
    unsigned short* Xb  = (unsigned short*)(ws);
    unsigned short* Wqb = (unsigned short*)(ws + (16ull << 20));
    unsigned short* Wkb = (unsigned short*)(ws + (24ull << 20));
    unsigned short* Wvb = (unsigned short*)(ws + (32ull << 20));
    unsigned short* Wob = (unsigned short*)(ws + (40ull << 20));
    unsigned short* qb  = (unsigned short*)(ws + (48ull << 20));
    unsigned short* kb  = (unsigned short*)(ws + (64ull << 20));
    unsigned short* vTb = (unsigned short*)(ws + (80ull << 20));
    unsigned short* ctx = Xb;

    // fp32 -> bf16, all tensors, one launch (24576 blocks)
    f2bf_all<<<dim3(24576), dim3(256), 0, stream>>>(
        hs, wq, wk, wv, wo, Xb, Wqb, Wkb, Wvb, Wob);

    // Fused QKV projection: A [4096x2048] x W [6144x2048]^T
    // BM=128 x BN=192, A-direct-from-global; grid 32x32 = 1024 blocks
    mfma_gemm_qkv<<<dim3(6144 / 192, M / 128), dim3(256), 0, stream>>>(
        Xb, Wqb, qb, kb, vTb);

    // RoPE: 16 rows/block, vectorized; blocks 0..4095 = q, 4096..8191 = k
    rope_bf16<<<dim3(2 * (Bb * Hh * Ll) / 16), dim3(256), 0, stream>>>(
        qb, kb, cosb, sinb);

    // Flash attention: 128 q-rows/block, 512 blocks (exactly 2/CU)
    flash_attn<<<dim3(Bb * Hh * (Ll / 128)), dim3(256), 0, stream>>>(qb, kb, vTb, ctx);

    // Output projection -> fp32 d_out (256 blocks = 1 full round)
    mfma_gemm_out<<<dim3(Dd / 128, M / 256), dim3(512), 0, stream>>>(
        ctx, Wob, out);
}

// Round 9
// 408.662 us; speedup vs baseline: 2.3481x; 1.3126x over previous
//
#include <hip/hip_runtime.h>

// Problem constants
constexpr int Bb = 2;
constexpr int Ll = 2048;
constexpr int Dd = 2048;
constexpr int Hh = 16;
constexpr int Hd = 128;
constexpr int M  = Bb * Ll;   // 4096

typedef __attribute__((ext_vector_type(8)))  short s16x8;   // 8 bf16 (4 VGPRs)
typedef __attribute__((ext_vector_type(4)))  float f32x4;   // 16x16 C/D
typedef __attribute__((ext_vector_type(16))) float f32x16;  // 32x32 C/D

__device__ __forceinline__ unsigned short f2bf(float f) {
    union { float f; unsigned u; } v; v.f = f;
    unsigned r = v.u + 0x7fffu + ((v.u >> 16) & 1u);   // RNE
    return (unsigned short)(r >> 16);
}
__device__ __forceinline__ float bf2f(unsigned short b) {
    union { unsigned u; float f; } v; v.u = ((unsigned)b) << 16;
    return v.f;
}
__device__ __forceinline__ float fast_exp2(float x) {
#if __has_builtin(__builtin_amdgcn_exp2f)
    return __builtin_amdgcn_exp2f(x);
#else
    return exp2f(x);
#endif
}

// async global->LDS, 16 B per lane; lds dest = wave-uniform base + lane*16
__device__ __forceinline__ void gld16(const void* g, void* l) {
#if __has_builtin(__builtin_amdgcn_global_load_lds)
    __builtin_amdgcn_global_load_lds(
        (const __attribute__((address_space(1))) unsigned int*)g,
        (__attribute__((address_space(3))) unsigned int*)l, 16, 0, 0);
#else
    int lane = threadIdx.x & 63;
    ((int4*)l)[lane] = ((const int4*)g)[0];
#endif
}

// ---------------------------------------------------------------------------
// fp32 -> bf16 conversion, all 5 tensors in ONE launch.
// Segments (exact 1024-elem blocks): X 8192 | wq 4096 | wk 4096 | wv 4096 |
// wo 4096 = 24576 blocks total.
// ---------------------------------------------------------------------------
__global__ __launch_bounds__(256)
void f2bf_all(const float* __restrict__ x,  const float* __restrict__ wq,
              const float* __restrict__ wk, const float* __restrict__ wv,
              const float* __restrict__ wo,
              unsigned short* __restrict__ Xb,  unsigned short* __restrict__ Wqb,
              unsigned short* __restrict__ Wkb, unsigned short* __restrict__ Wvb,
              unsigned short* __restrict__ Wob)
{
    int bid = blockIdx.x;
    const float* in; unsigned short* out; int off;
    if      (bid <  8192) { in = x;  out = Xb;  off = bid; }
    else if (bid < 12288) { in = wq; out = Wqb; off = bid - 8192; }
    else if (bid < 16384) { in = wk; out = Wkb; off = bid - 12288; }
    else if (bid < 20480) { in = wv; out = Wvb; off = bid - 16384; }
    else                  { in = wo; out = Wob; off = bid - 20480; }
    int i = (off * 256 + threadIdx.x) * 4;
    float4 v = *(const float4*)(in + i);
    ushort4 o;
    o.x = f2bf(v.x); o.y = f2bf(v.y); o.z = f2bf(v.z); o.w = f2bf(v.w);
    *(ushort4*)(out + i) = o;
}

// ---------------------------------------------------------------------------
// Fused QKV GEMM (R6-proven, 106 µs / 42% MfmaUtil): C = A * Wall^T.
// A [4096][2048] bf16, Wall [6144][2048] (wq;wk;wv stacked).
// BM=128 x BN=192, BK=64, 256 threads = 4 waves (2M x 2N), per-wave 64x96.
// LDS: 2 slots x 40 KiB = 80 KiB -> 2 blocks/CU; blocks barrier-independent
// so one block's drain is covered by the other's MFMAs (m114).
// Per K-tile: read ks0 frags -> issue ALL 10 gld_lds for t+1 into slot^1 ->
// 24 MFMA -> ks1 frags -> 24 MFMA -> vmcnt(0) -> one barrier.
// XOR swizzle (T2) both-sides.  Grid 32x32 = 1024 blocks = 2 rounds of 512.
// ---------------------------------------------------------------------------
__global__ __launch_bounds__(256, 2)
void mfma_gemm_qkv(const unsigned short* __restrict__ A,
                   const unsigned short* __restrict__ Wall,
                   unsigned short* __restrict__ Oq,
                   unsigned short* __restrict__ Ok,
                   unsigned short* __restrict__ Ov)
{
    constexpr int K  = 2048;
    constexpr int NT = K / 64;              // 32 K-tiles
    constexpr int BM = 128, BN = 192;
    constexpr int SLOT_US = (BM + BN) * 64; // 20480 ushorts = 40 KiB

    __shared__ unsigned short lds[2 * SLOT_US];   // 80 KiB -> 2 blocks/CU

    const int t    = threadIdx.x;
    const int w    = t >> 6, lane = t & 63;
    const int wm   = w >> 1, wn = w & 1;          // 2M x 2N
    const int m0   = blockIdx.y * BM, n0 = blockIdx.x * BN;
    const int r16  = lane & 15, q4 = lane >> 4;
    const int lxor = (r16 & 7) << 4;              // read-side swizzle XOR

    // staging lane constants: 8 lanes per 128B row; swizzled source column
    const int srow8 = lane >> 3;
    const int sgcol = (((lane & 7) ^ srow8) << 4);
    const char* Agb = (const char*)A;
    const char* Wgb = (const char*)Wall;

    f32x4 acc[4][6];
#pragma unroll
    for (int i = 0; i < 4; ++i)
#pragma unroll
        for (int j = 0; j < 6; ++j)
            acc[i][j] = (f32x4){0.f, 0.f, 0.f, 0.f};

// stage full K-tile: A 16 gld (ia=w*4+p), B 24 gld (ib=w*6+p); 10 per wave
#define STAGE_ALL(tt, sl) do {                                               \
    _Pragma("unroll") for (int p = 0; p < 4; ++p) {                          \
        int ia_ = w * 4 + p;                                                 \
        gld16(Agb + (size_t)(m0 + ia_ * 8 + srow8) * (K * 2) + (tt) * 128 + sgcol, \
              &lds[(sl) * SLOT_US + ia_ * 512]);                             \
    }                                                                        \
    _Pragma("unroll") for (int p = 0; p < 6; ++p) {                          \
        int ib_ = w * 6 + p;                                                 \
        gld16(Wgb + (size_t)(n0 + ib_ * 8 + srow8) * (K * 2) + (tt) * 128 + sgcol, \
              &lds[(sl) * SLOT_US + BM * 64 + ib_ * 512]);                   \
    }                                                                        \
} while (0)

#define MFMA24() do {                                                        \
    __builtin_amdgcn_s_setprio(1);                                           \
    _Pragma("unroll") for (int mi = 0; mi < 4; ++mi)                         \
    _Pragma("unroll") for (int ni = 0; ni < 6; ++ni)                         \
        acc[mi][ni] = __builtin_amdgcn_mfma_f32_16x16x32_bf16(                \
            a[mi], b[ni], acc[mi][ni], 0, 0, 0);                             \
    __builtin_amdgcn_s_setprio(0);                                           \
} while (0)

    // prologue: stage tile 0 into slot 0
    STAGE_ALL(0, 0);
    asm volatile("s_waitcnt vmcnt(0)" ::: "memory");
    __builtin_amdgcn_s_barrier();
    asm volatile("" ::: "memory");

    for (int tt = 0; tt < NT; ++tt) {
        const int slot = tt & 1;
        const char* Ab = (const char*)&lds[slot * SLOT_US];
        const char* Bp = (const char*)&lds[slot * SLOT_US + BM * 64];
        const int c0 = (q4 * 16) ^ lxor;         // ksub0 byte col (swizzled)
        const int c1 = (64 + q4 * 16) ^ lxor;    // ksub1

        s16x8 a[4], b[6];

        // ks0 frags
#pragma unroll
        for (int mi = 0; mi < 4; ++mi)
            a[mi] = *(const s16x8*)(Ab + (wm * 64 + mi * 16 + r16) * 128 + c0);
#pragma unroll
        for (int ni = 0; ni < 6; ++ni)
            b[ni] = *(const s16x8*)(Bp + (wn * 96 + ni * 16 + r16) * 128 + c0);
        // issue next tile's staging early (distance ~1 tile to the wait)
        if (tt + 1 < NT) STAGE_ALL(tt + 1, slot ^ 1);
        MFMA24();

        // ks1 frags
#pragma unroll
        for (int mi = 0; mi < 4; ++mi)
            a[mi] = *(const s16x8*)(Ab + (wm * 64 + mi * 16 + r16) * 128 + c1);
#pragma unroll
        for (int ni = 0; ni < 6; ++ni)
            b[ni] = *(const s16x8*)(Bp + (wn * 96 + ni * 16 + r16) * 128 + c1);
        MFMA24();

        asm volatile("s_waitcnt vmcnt(0)" ::: "memory");  // t+1 staged
        __builtin_amdgcn_s_barrier();
        asm volatile("" ::: "memory");
    }
#undef STAGE_ALL
#undef MFMA24

    // epilogue: per frag-column routing (nb 16-aligned -> wave-uniform nsel)
#pragma unroll
    for (int ni = 0; ni < 6; ++ni) {
        int nb   = n0 + wn * 96 + ni * 16;
        int nsel = nb >> 11;                // 0=q, 1=k, 2=v
        int nr   = nb & 2047;
        int h    = nr >> 7;
        int d    = (nr & 127) + r16;
        if (nsel < 2) {
            unsigned short* O = nsel ? Ok : Oq;
#pragma unroll
            for (int mi = 0; mi < 4; ++mi)
#pragma unroll
                for (int r = 0; r < 4; ++r) {
                    int m = m0 + wm * 64 + mi * 16 + q4 * 4 + r;
                    int b = m >> 11, l = m & 2047;
                    O[(((size_t)b * Hh + h) * Ll + l) * Hd + d] =
                        f2bf(acc[mi][ni][r]);
                }
        } else {
            // v: transposed store [b][h][d][l]; lane holds 4 consecutive l
#pragma unroll
            for (int mi = 0; mi < 4; ++mi) {
                int mb = m0 + wm * 64 + mi * 16 + q4 * 4;
                int b = mb >> 11, l = mb & 2047;
                ushort4 pk;
                pk.x = f2bf(acc[mi][ni][0]);
                pk.y = f2bf(acc[mi][ni][1]);
                pk.z = f2bf(acc[mi][ni][2]);
                pk.w = f2bf(acc[mi][ni][3]);
                *(ushort4*)&Ov[(((size_t)b * Hh + h) * Hd + d) * Ll + l] = pk;
            }
        }
    }
}

// ---------------------------------------------------------------------------
// Out-projection GEMM (proven r3 structure): C = A * W^T, fp32 store.
// BM=256 x BN=128, BK=64, 8 waves (4M x 2N), per-wave 64x64, 3 LDS slots,
// counted vmcnt(6), XOR swizzle.  Grid 16x16 = 256 blocks = 1 full round.
// ---------------------------------------------------------------------------
__global__ __launch_bounds__(512, 2)
void mfma_gemm_out(const unsigned short* __restrict__ A,
                   const unsigned short* __restrict__ W,
                   float* __restrict__ FO)
{
    constexpr int K  = 2048;
    constexpr int NT = K / 64;          // 32 K-tiles
    constexpr int SLOT_US = 24576;      // A 16384 + B 8192

    __shared__ unsigned short lds[3 * SLOT_US];   // 144 KiB

    const int t    = threadIdx.x;
    const int w    = t >> 6, lane = t & 63;
    const int wm   = w >> 1, wn = w & 1;
    const int m0   = blockIdx.y * 256, n0 = blockIdx.x * 128;
    const int r16  = lane & 15, q4 = lane >> 4;
    const int lxor = (r16 & 7) << 4;

    const int srow8 = lane >> 3;
    const int sgcol = (((lane & 7) ^ srow8) << 4);
    const char* Agb = (const char*)A;
    const char* Wgb = (const char*)W;

    f32x4 acc[4][4];
#pragma unroll
    for (int i = 0; i < 4; ++i)
#pragma unroll
        for (int j = 0; j < 4; ++j)
            acc[i][j] = (f32x4){0.f, 0.f, 0.f, 0.f};

    s16x8 af[4], bf[4];

#define STAGE_A(tt, sl, p) do {                                              \
    int ia_ = w * 4 + (p);                                                   \
    gld16(Agb + (size_t)(m0 + ia_ * 8 + srow8) * (K * 2) + (tt) * 128 + sgcol, \
          &lds[(sl) * SLOT_US + ia_ * 512]); } while (0)
#define STAGE_B(tt, sl, p) do {                                              \
    int ib_ = w * 2 + (p);                                                   \
    gld16(Wgb + (size_t)(n0 + ib_ * 8 + srow8) * (K * 2) + (tt) * 128 + sgcol, \
          &lds[(sl) * SLOT_US + 16384 + ib_ * 512]); } while (0)

#define LOAD_FRAGS(sl, ksub) do {                                            \
    const char* Ab_ = (const char*)&lds[(sl) * SLOT_US];                     \
    const char* Bb_ = (const char*)&lds[(sl) * SLOT_US + 16384];             \
    int cc_ = ((ksub) * 64 + q4 * 16) ^ lxor;                                \
    _Pragma("unroll") for (int mi = 0; mi < 4; ++mi)                         \
        af[mi] = *(const s16x8*)(Ab_ + (wm * 64 + mi * 16 + r16) * 128 + cc_); \
    _Pragma("unroll") for (int ni = 0; ni < 4; ++ni)                         \
        bf[ni] = *(const s16x8*)(Bb_ + (wn * 64 + ni * 16 + r16) * 128 + cc_); \
} while (0)

#define DO_MFMA() do {                                                       \
    __builtin_amdgcn_s_setprio(1);                                           \
    _Pragma("unroll") for (int mi = 0; mi < 4; ++mi)                         \
    _Pragma("unroll") for (int ni = 0; ni < 4; ++ni)                         \
        acc[mi][ni] = __builtin_amdgcn_mfma_f32_16x16x32_bf16(                \
            af[mi], bf[ni], acc[mi][ni], 0, 0, 0);                           \
    __builtin_amdgcn_s_setprio(0);                                           \
} while (0)

    STAGE_A(0, 0, 0); STAGE_A(0, 0, 1); STAGE_B(0, 0, 0);
    STAGE_A(0, 0, 2); STAGE_A(0, 0, 3); STAGE_B(0, 0, 1);
    STAGE_A(1, 1, 0); STAGE_A(1, 1, 1); STAGE_B(1, 1, 0);
    STAGE_A(1, 1, 2); STAGE_A(1, 1, 3); STAGE_B(1, 1, 1);
    asm volatile("s_waitcnt vmcnt(6)" ::: "memory");
    __builtin_amdgcn_s_barrier();
    asm volatile("" ::: "memory");

    int slot = 0;
    for (int tt = 0; tt < NT; ++tt) {
        int snx = slot + 2; if (snx >= 3) snx -= 3;
        const bool pf = (tt + 2 < NT);

        LOAD_FRAGS(slot, 0);
        if (pf) { STAGE_A(tt + 2, snx, 0); STAGE_A(tt + 2, snx, 1); STAGE_B(tt + 2, snx, 0); }
        asm volatile("" ::: "memory");
        __builtin_amdgcn_s_barrier();
        asm volatile("s_waitcnt lgkmcnt(0)" ::: "memory");
        DO_MFMA();
        asm volatile("" ::: "memory");
        __builtin_amdgcn_s_barrier();
        asm volatile("" ::: "memory");

        LOAD_FRAGS(slot, 1);
        if (pf) { STAGE_A(tt + 2, snx, 2); STAGE_A(tt + 2, snx, 3); STAGE_B(tt + 2, snx, 1); }
        asm volatile("" ::: "memory");
        __builtin_amdgcn_s_barrier();
        asm volatile("s_waitcnt lgkmcnt(0)" ::: "memory");
        DO_MFMA();
        if (pf)               asm volatile("s_waitcnt vmcnt(6)" ::: "memory");
        else if (tt + 1 < NT) asm volatile("s_waitcnt vmcnt(0)" ::: "memory");
        asm volatile("" ::: "memory");
        __builtin_amdgcn_s_barrier();
        asm volatile("" ::: "memory");

        slot = (slot == 2) ? 0 : slot + 1;
    }
#undef STAGE_A
#undef STAGE_B
#undef LOAD_FRAGS
#undef DO_MFMA

#pragma unroll
    for (int mi = 0; mi < 4; ++mi)
#pragma unroll
        for (int ni = 0; ni < 4; ++ni) {
            int n = n0 + wn * 64 + ni * 16 + r16;
#pragma unroll
            for (int r = 0; r < 4; ++r) {
                int m = m0 + wm * 64 + mi * 16 + q4 * 4 + r;
                FO[(size_t)m * Dd + n] = acc[mi][ni][r];
            }
        }
}

// ---------------------------------------------------------------------------
// RoPE in-place on bf16 q,k, vectorized short8 (G13).  16 threads/row,
// 16 rows/block; row lives in one wave.  q scaled by log2(e)/sqrt(128).
// grid: 8192 blocks (0..4095 = q, 4096..8191 = k).
// ---------------------------------------------------------------------------
__global__ __launch_bounds__(256)
void rope_bf16(unsigned short* __restrict__ q, unsigned short* __restrict__ k,
               const float* __restrict__ cosb, const float* __restrict__ sinb)
{
    const float QS = 0.1275175f;           // log2(e)/sqrt(128)
    const int t = threadIdx.x;
    int rblk = blockIdx.x;
    unsigned short* base;
    float sc;
    if (rblk < 4096) { base = q; sc = QS; }
    else             { base = k; sc = 1.0f; rblk -= 4096; }

    const int row = rblk * 16 + (t >> 4);  // [0, B*H*L)
    const int l   = row & (Ll - 1);
    const int d0  = (t & 15) * 8;
    unsigned short* xr = base + (size_t)row * Hd;

    s16x8 v0 = *(const s16x8*)(xr + d0);
    s16x8 vp = *(const s16x8*)(xr + (d0 ^ 64));
    const float* cp = cosb + (size_t)l * Hd + d0;
    const float* sp = sinb + (size_t)l * Hd + d0;
    float4 c0 = *(const float4*)cp,       c1 = *(const float4*)(cp + 4);
    float4 sa = *(const float4*)sp,       sb = *(const float4*)(sp + 4);
    const float cc[8] = {c0.x, c0.y, c0.z, c0.w, c1.x, c1.y, c1.z, c1.w};
    const float ss[8] = {sa.x, sa.y, sa.z, sa.w, sb.x, sb.y, sb.z, sb.w};
    const float sgn = (d0 < 64) ? -1.f : 1.f;

    s16x8 o;
#pragma unroll
    for (int j = 0; j < 8; ++j) {
        float a = bf2f((unsigned short)v0[j]);
        float p = bf2f((unsigned short)vp[j]);
        float res = fmaf(a, cc[j], sgn * p * ss[j]) * sc;
        o[j] = (short)f2bf(res);
    }
    asm volatile("" ::: "memory");         // loads (both halves) before store
    *(s16x8*)(xr + d0) = o;
}

// ---------------------------------------------------------------------------
// Flash attention, 2 Q-groups per wave (read-amortized): each wave owns 64
// q-rows as two 32-row groups g=0,1 sharing every staged K/V fragment read:
// b0/b1 feed 4 MFMAs (2 groups x 2 key-halves), vf feeds 2 -> ds_read per
// MFMA drops 1.13 -> 0.625 (kernel is LDS-throughput-bound: was ~3460 cyc
// LDS vs ~510 MFMA per CU-tile).  Block = 4 waves x 64 rows = 256 q-rows;
// grid 256 = 1 block/CU; LDS 96 KiB (Ks 2x16K, Vs 2x16K, Ps 8x4K).
// __launch_bounds__(256,1): 1 wave/SIMD -> 512-VGPR budget for the ~300
// live regs (o0/o1 128 + qf0/qf1 64 + lacc 32 + transients) -- no spill
// (m08: clean through 450).  Async gld_lds double-buffer staging, XOR
// swizzle, one barrier per tile, setprio on MFMA clusters (all r3-proven).
// ---------------------------------------------------------------------------
__global__ __launch_bounds__(256, 1)
void flash_attn(const unsigned short* __restrict__ q,
                const unsigned short* __restrict__ k,
                const unsigned short* __restrict__ vT,
                unsigned short* __restrict__ ctx)
{
    __shared__ unsigned short Ks[2][64 * 128];   // [key][d] linear
    __shared__ unsigned short Vs[2][128 * 64];   // [d][key] linear
    __shared__ unsigned short Ps[8][32 * 64];    // per (wave,group) [m][key]

    const int t = threadIdx.x;
    const int w = t >> 6, lane = t & 63;
    const int n32 = lane & 31, half = lane >> 5;
    const int bh = blockIdx.x >> 3;              // 8 q-tiles of 256 per (b,h)
    const int l0 = (blockIdx.x & 7) * 256;

    const unsigned short* qb = q  + ((size_t)bh * Ll + l0) * Hd;
    const unsigned short* kb = k  + (size_t)bh * Ll * Hd;
    const unsigned short* vb = vT + (size_t)bh * Hd * Ll;

    const int k_r = lane >> 4, k_u = lane & 15;  // K: 4 rows x 256 B per instr
    const int v_r = lane >> 3, v_u = lane & 7;   // V: 8 rows x 128 B per instr

#define STAGE(J0, bsel) do {                                                  \
    _Pragma("unroll") for (int p = 0; p < 4; ++p) {                           \
        int j_ = w * 4 + p;                                                   \
        int row_ = j_ * 4 + k_r;                                              \
        gld16(kb + (size_t)((J0) + row_) * Hd + ((k_u ^ (row_ & 7)) * 8),     \
              &Ks[bsel][j_ * 512]);                                           \
    }                                                                         \
    _Pragma("unroll") for (int p = 0; p < 4; ++p) {                           \
        int j_ = w * 4 + p;                                                   \
        int row_ = j_ * 8 + v_r;                                              \
        gld16(vb + (size_t)row_ * Ll + (J0) + ((v_u ^ (row_ & 7)) * 8),       \
              &Vs[bsel][j_ * 512]);                                           \
    }                                                                         \
} while (0)

    // Q A-frags for both groups, direct from global
    s16x8 qf0[8], qf1[8];
#pragma unroll
    for (int ks = 0; ks < 8; ++ks) {
        qf0[ks] = *(const s16x8*)(qb + (size_t)((w * 2 + 0) * 32 + n32) * Hd + ks * 16 + half * 8);
        qf1[ks] = *(const s16x8*)(qb + (size_t)((w * 2 + 1) * 32 + n32) * Hd + ks * 16 + half * 8);
    }

    f32x16 o0[4], o1[4];
    float la0[16], la1[16];
#pragma unroll
    for (int nt = 0; nt < 4; ++nt)
#pragma unroll
        for (int r = 0; r < 16; ++r) { o0[nt][r] = 0.f; o1[nt][r] = 0.f; }
#pragma unroll
    for (int r = 0; r < 16; ++r) { la0[r] = 0.f; la1[r] = 0.f; }

    unsigned short* Pw0 = Ps[w * 2 + 0];
    unsigned short* Pw1 = Ps[w * 2 + 1];
    const int psw = (n32 & 7) << 3;              // read-side swizzle (row n32)

    STAGE(0, 0);
    __syncthreads();

    int buf = 0;
    for (int j0 = 0; j0 < Ll; j0 += 64) {
        if (j0 + 64 < Ll) STAGE(j0 + 64, buf ^ 1);   // in flight across compute

        // S = Q K^T, both groups share b0/b1 (1 read : 2 MFMA)
        f32x16 s00, s01, s10, s11;
#pragma unroll
        for (int r = 0; r < 16; ++r) { s00[r] = 0.f; s01[r] = 0.f; s10[r] = 0.f; s11[r] = 0.f; }
        __builtin_amdgcn_s_setprio(1);
#pragma unroll
        for (int ks = 0; ks < 8; ++ks) {
            int kc = (ks * 16 + half * 8) ^ psw;
            s16x8 b0 = *(const s16x8*)&Ks[buf][n32 * 128 + kc];
            s16x8 b1 = *(const s16x8*)&Ks[buf][(32 + n32) * 128 + kc];
            s00 = __builtin_amdgcn_mfma_f32_32x32x16_bf16(qf0[ks], b0, s00, 0, 0, 0);
            s01 = __builtin_amdgcn_mfma_f32_32x32x16_bf16(qf0[ks], b1, s01, 0, 0, 0);
            s10 = __builtin_amdgcn_mfma_f32_32x32x16_bf16(qf1[ks], b0, s10, 0, 0, 0);
            s11 = __builtin_amdgcn_mfma_f32_32x32x16_bf16(qf1[ks], b1, s11, 0, 0, 0);
        }
        __builtin_amdgcn_s_setprio(0);

        // P = exp2(S) (scale pre-folded into q); store bf16 to Ps; l += p
#pragma unroll
        for (int r = 0; r < 16; ++r) {
            int mrow = (r & 3) + 8 * (r >> 2) + 4 * half;
            int sw = (mrow & 7) << 3;
            float p00 = fast_exp2(s00[r]);
            float p01 = fast_exp2(s01[r]);
            float p10 = fast_exp2(s10[r]);
            float p11 = fast_exp2(s11[r]);
            la0[r] += p00 + p01;
            la1[r] += p10 + p11;
            union { float f; unsigned u; } u0, u1, u2, u3;
            u0.f = p00; u1.f = p01; u2.f = p10; u3.f = p11;
            Pw0[mrow * 64 + (n32 ^ sw)]        = (unsigned short)((u0.u + 0x8000u) >> 16);
            Pw0[mrow * 64 + ((32 + n32) ^ sw)] = (unsigned short)((u1.u + 0x8000u) >> 16);
            Pw1[mrow * 64 + (n32 ^ sw)]        = (unsigned short)((u2.u + 0x8000u) >> 16);
            Pw1[mrow * 64 + ((32 + n32) ^ sw)] = (unsigned short)((u3.u + 0x8000u) >> 16);
        }

        // O += P V, both groups share vf (1 read : 2 MFMA); wave-private
        __builtin_amdgcn_s_setprio(1);
#pragma unroll
        for (int kst = 0; kst < 4; ++kst) {
            int cc = (kst * 16 + half * 8) ^ psw;
            s16x8 pa = *(const s16x8*)&Pw0[n32 * 64 + cc];
            s16x8 pb = *(const s16x8*)&Pw1[n32 * 64 + cc];
#pragma unroll
            for (int nt = 0; nt < 4; ++nt) {
                s16x8 vf = *(const s16x8*)&Vs[buf][(nt * 32 + n32) * 64 + cc];
                o0[nt] = __builtin_amdgcn_mfma_f32_32x32x16_bf16(pa, vf, o0[nt], 0, 0, 0);
                o1[nt] = __builtin_amdgcn_mfma_f32_32x32x16_bf16(pb, vf, o1[nt], 0, 0, 0);
            }
        }
        __builtin_amdgcn_s_setprio(0);

        __syncthreads();     // drains vmcnt(0): next tile staged; buffer swap
        buf ^= 1;
    }
#undef STAGE

    // epilogue: reduce l over the 32 key-lanes, both groups
    float li0[16], li1[16];
#pragma unroll
    for (int r = 0; r < 16; ++r) {
        float s = la0[r];
        s += __shfl_xor(s, 1, 64);
        s += __shfl_xor(s, 2, 64);
        s += __shfl_xor(s, 4, 64);
        s += __shfl_xor(s, 8, 64);
        s += __shfl_xor(s, 16, 64);
        li0[r] = 1.0f / s;
        float z = la1[r];
        z += __shfl_xor(z, 1, 64);
        z += __shfl_xor(z, 2, 64);
        z += __shfl_xor(z, 4, 64);
        z += __shfl_xor(z, 8, 64);
        z += __shfl_xor(z, 16, 64);
        li1[r] = 1.0f / z;
    }

    const int b = bh >> 4, h = bh & 15;
#pragma unroll
    for (int nt = 0; nt < 4; ++nt)
#pragma unroll
        for (int r = 0; r < 16; ++r) {
            int mrow = (r & 3) + 8 * (r >> 2) + 4 * half;
            int lq0 = l0 + (w * 2 + 0) * 32 + mrow;
            int lq1 = l0 + (w * 2 + 1) * 32 + mrow;
            ctx[((size_t)(b * Ll + lq0)) * Dd + h * Hd + nt * 32 + n32] =
                f2bf(o0[nt][r] * li0[r]);
            ctx[((size_t)(b * Ll + lq1)) * Dd + h * Hd + nt * 32 + n32] =
                f2bf(o1[nt][r] * li1[r]);
        }
}

// ---------------------------------------------------------------------------
// Workspace (96 MB): [Xb 16M][Wq 8M][Wk 8M][Wv 8M][Wo 8M][q 16M][k 16M][vT 16M]
// Wq/Wk/Wv contiguous -> fused QKV GEMM reads them as one [6144][2048] W.
// ctx reuses the Xb slot (X dead after QKV GEMM).
// ---------------------------------------------------------------------------
extern "C" void kernel_launch(void* const* d_in, const int* in_sizes, int n_in,
                              void* d_out, int out_size, void* d_ws, size_t ws_size,
                              hipStream_t stream)
{
    const float* hs   = (const float*)d_in[0];
    const float* cosb = (const float*)d_in[1];
    const float* sinb = (const float*)d_in[2];
    const float* wq   = (const float*)d_in[3];
    const float* wk   = (const float*)d_in[4];
    const float* wv   = (const float*)d_in[5];
    const float* wo   = (const float*)d_in[6];
    float* out = (float*)d_out;

    char* ws = (char*)d_ws;
    unsigned short* Xb  = (unsigned short*)(ws);
    unsigned short* Wqb = (unsigned short*)(ws + (16ull << 20));
    unsigned short* Wkb = (unsigned short*)(ws + (24ull << 20));
    unsigned short* Wvb = (unsigned short*)(ws + (32ull << 20));
    unsigned short* Wob = (unsigned short*)(ws + (40ull << 20));
    unsigned short* qb  = (unsigned short*)(ws + (48ull << 20));
    unsigned short* kb  = (unsigned short*)(ws + (64ull << 20));
    unsigned short* vTb = (unsigned short*)(ws + (80ull << 20));
    unsigned short* ctx = Xb;

    // fp32 -> bf16, all tensors, one launch (24576 blocks)
    f2bf_all<<<dim3(24576), dim3(256), 0, stream>>>(
        hs, wq, wk, wv, wo, Xb, Wqb, Wkb, Wvb, Wob);

    // Fused QKV projection: A [4096x2048] x W [6144x2048]^T
    // BM=128 x BN=192: grid 32x32 = 1024 blocks, 2/CU co-resident, 2 rounds
    mfma_gemm_qkv<<<dim3(6144 / 192, M / 128), dim3(256), 0, stream>>>(
        Xb, Wqb, qb, kb, vTb);

    // RoPE: 16 rows/block, vectorized; blocks 0..4095 = q, 4096..8191 = k
    rope_bf16<<<dim3(2 * (Bb * Hh * Ll) / 16), dim3(256), 0, stream>>>(
        qb, kb, cosb, sinb);

    // Flash attention: 256 q-rows/block, 256 blocks = 1/CU
    flash_attn<<<dim3(Bb * Hh * (Ll / 256)), dim3(256), 0, stream>>>(qb, kb, vTb, ctx);

    // Output projection -> fp32 d_out (256 blocks = 1 full round)
    mfma_gemm_out<<<dim3(Dd / 128, M / 256), dim3(512), 0, stream>>>(
        ctx, Wob, out);
}

// Round 12
// 379.625 us; speedup vs baseline: 2.5277x; 1.0765x over previous
//
#include <hip/hip_runtime.h>

// Problem constants
constexpr int Bb = 2;
constexpr int Ll = 2048;
constexpr int Dd = 2048;
constexpr int Hh = 16;
constexpr int Hd = 128;
constexpr int M  = Bb * Ll;   // 4096

typedef __attribute__((ext_vector_type(8)))  short s16x8;   // 8 bf16 (4 VGPRs)
typedef __attribute__((ext_vector_type(4)))  float f32x4;   // 16x16 C/D
typedef __attribute__((ext_vector_type(16))) float f32x16;  // 32x32 C/D

__device__ __forceinline__ unsigned short f2bf(float f) {
    union { float f; unsigned u; } v; v.f = f;
    unsigned r = v.u + 0x7fffu + ((v.u >> 16) & 1u);   // RNE
    return (unsigned short)(r >> 16);
}
__device__ __forceinline__ float bf2f(unsigned short b) {
    union { unsigned u; float f; } v; v.u = ((unsigned)b) << 16;
    return v.f;
}
__device__ __forceinline__ float fast_exp2(float x) {
#if __has_builtin(__builtin_amdgcn_exp2f)
    return __builtin_amdgcn_exp2f(x);
#else
    return exp2f(x);
#endif
}

// async global->LDS, 16 B per lane; lds dest = wave-uniform base + lane*16
__device__ __forceinline__ void gld16(const void* g, void* l) {
#if __has_builtin(__builtin_amdgcn_global_load_lds)
    __builtin_amdgcn_global_load_lds(
        (const __attribute__((address_space(1))) unsigned int*)g,
        (__attribute__((address_space(3))) unsigned int*)l, 16, 0, 0);
#else
    int lane = threadIdx.x & 63;
    ((int4*)l)[lane] = ((const int4*)g)[0];
#endif
}

// ---------------------------------------------------------------------------
// fp32 -> bf16 conversion, all 5 tensors in ONE launch.
// Segments (exact 1024-elem blocks): X 8192 | wq 4096 | wk 4096 | wv 4096 |
// wo 4096 = 24576 blocks total.
// ---------------------------------------------------------------------------
__global__ __launch_bounds__(256)
void f2bf_all(const float* __restrict__ x,  const float* __restrict__ wq,
              const float* __restrict__ wk, const float* __restrict__ wv,
              const float* __restrict__ wo,
              unsigned short* __restrict__ Xb,  unsigned short* __restrict__ Wqb,
              unsigned short* __restrict__ Wkb, unsigned short* __restrict__ Wvb,
              unsigned short* __restrict__ Wob)
{
    int bid = blockIdx.x;
    const float* in; unsigned short* out; int off;
    if      (bid <  8192) { in = x;  out = Xb;  off = bid; }
    else if (bid < 12288) { in = wq; out = Wqb; off = bid - 8192; }
    else if (bid < 16384) { in = wk; out = Wkb; off = bid - 12288; }
    else if (bid < 20480) { in = wv; out = Wvb; off = bid - 16384; }
    else                  { in = wo; out = Wob; off = bid - 20480; }
    int i = (off * 256 + threadIdx.x) * 4;
    float4 v = *(const float4*)(in + i);
    ushort4 o;
    o.x = f2bf(v.x); o.y = f2bf(v.y); o.z = f2bf(v.z); o.w = f2bf(v.w);
    *(ushort4*)(out + i) = o;
}

// ---------------------------------------------------------------------------
// Fused QKV GEMM (R6-proven, 106 µs / 42% MfmaUtil): C = A * Wall^T.
// A [4096][2048] bf16, Wall [6144][2048] (wq;wk;wv stacked).
// BM=128 x BN=192, BK=64, 256 threads = 4 waves (2M x 2N), per-wave 64x96.
// LDS: 2 slots x 40 KiB = 80 KiB -> 2 blocks/CU; blocks barrier-independent
// so one block's drain is covered by the other's MFMAs (m114).
// Per K-tile: read ks0 frags -> issue ALL 10 gld_lds for t+1 into slot^1 ->
// 24 MFMA -> ks1 frags -> 24 MFMA -> vmcnt(0) -> one barrier.
// XOR swizzle (T2) both-sides.  Grid 32x32 = 1024 blocks = 2 rounds of 512.
// ---------------------------------------------------------------------------
__global__ __launch_bounds__(256, 2)
void mfma_gemm_qkv(const unsigned short* __restrict__ A,
                   const unsigned short* __restrict__ Wall,
                   unsigned short* __restrict__ Oq,
                   unsigned short* __restrict__ Ok,
                   unsigned short* __restrict__ Ov)
{
    constexpr int K  = 2048;
    constexpr int NT = K / 64;              // 32 K-tiles
    constexpr int BM = 128, BN = 192;
    constexpr int SLOT_US = (BM + BN) * 64; // 20480 ushorts = 40 KiB

    __shared__ unsigned short lds[2 * SLOT_US];   // 80 KiB -> 2 blocks/CU

    const int t    = threadIdx.x;
    const int w    = t >> 6, lane = t & 63;
    const int wm   = w >> 1, wn = w & 1;          // 2M x 2N
    const int m0   = blockIdx.y * BM, n0 = blockIdx.x * BN;
    const int r16  = lane & 15, q4 = lane >> 4;
    const int lxor = (r16 & 7) << 4;              // read-side swizzle XOR

    // staging lane constants: 8 lanes per 128B row; swizzled source column
    const int srow8 = lane >> 3;
    const int sgcol = (((lane & 7) ^ srow8) << 4);
    const char* Agb = (const char*)A;
    const char* Wgb = (const char*)Wall;

    f32x4 acc[4][6];
#pragma unroll
    for (int i = 0; i < 4; ++i)
#pragma unroll
        for (int j = 0; j < 6; ++j)
            acc[i][j] = (f32x4){0.f, 0.f, 0.f, 0.f};

// stage full K-tile: A 16 gld (ia=w*4+p), B 24 gld (ib=w*6+p); 10 per wave
#define STAGE_ALL(tt, sl) do {                                               \
    _Pragma("unroll") for (int p = 0; p < 4; ++p) {                          \
        int ia_ = w * 4 + p;                                                 \
        gld16(Agb + (size_t)(m0 + ia_ * 8 + srow8) * (K * 2) + (tt) * 128 + sgcol, \
              &lds[(sl) * SLOT_US + ia_ * 512]);                             \
    }                                                                        \
    _Pragma("unroll") for (int p = 0; p < 6; ++p) {                          \
        int ib_ = w * 6 + p;                                                 \
        gld16(Wgb + (size_t)(n0 + ib_ * 8 + srow8) * (K * 2) + (tt) * 128 + sgcol, \
              &lds[(sl) * SLOT_US + BM * 64 + ib_ * 512]);                   \
    }                                                                        \
} while (0)

#define MFMA24() do {                                                        \
    __builtin_amdgcn_s_setprio(1);                                           \
    _Pragma("unroll") for (int mi = 0; mi < 4; ++mi)                         \
    _Pragma("unroll") for (int ni = 0; ni < 6; ++ni)                         \
        acc[mi][ni] = __builtin_amdgcn_mfma_f32_16x16x32_bf16(                \
            a[mi], b[ni], acc[mi][ni], 0, 0, 0);                             \
    __builtin_amdgcn_s_setprio(0);                                           \
} while (0)

    // prologue: stage tile 0 into slot 0
    STAGE_ALL(0, 0);
    asm volatile("s_waitcnt vmcnt(0)" ::: "memory");
    __builtin_amdgcn_s_barrier();
    asm volatile("" ::: "memory");

    for (int tt = 0; tt < NT; ++tt) {
        const int slot = tt & 1;
        const char* Ab = (const char*)&lds[slot * SLOT_US];
        const char* Bp = (const char*)&lds[slot * SLOT_US + BM * 64];
        const int c0 = (q4 * 16) ^ lxor;         // ksub0 byte col (swizzled)
        const int c1 = (64 + q4 * 16) ^ lxor;    // ksub1

        s16x8 a[4], b[6];

        // ks0 frags
#pragma unroll
        for (int mi = 0; mi < 4; ++mi)
            a[mi] = *(const s16x8*)(Ab + (wm * 64 + mi * 16 + r16) * 128 + c0);
#pragma unroll
        for (int ni = 0; ni < 6; ++ni)
            b[ni] = *(const s16x8*)(Bp + (wn * 96 + ni * 16 + r16) * 128 + c0);
        // issue next tile's staging early (distance ~1 tile to the wait)
        if (tt + 1 < NT) STAGE_ALL(tt + 1, slot ^ 1);
        MFMA24();

        // ks1 frags
#pragma unroll
        for (int mi = 0; mi < 4; ++mi)
            a[mi] = *(const s16x8*)(Ab + (wm * 64 + mi * 16 + r16) * 128 + c1);
#pragma unroll
        for (int ni = 0; ni < 6; ++ni)
            b[ni] = *(const s16x8*)(Bp + (wn * 96 + ni * 16 + r16) * 128 + c1);
        MFMA24();

        asm volatile("s_waitcnt vmcnt(0)" ::: "memory");  // t+1 staged
        __builtin_amdgcn_s_barrier();
        asm volatile("" ::: "memory");
    }
#undef STAGE_ALL
#undef MFMA24

    // epilogue: per frag-column routing (nb 16-aligned -> wave-uniform nsel)
#pragma unroll
    for (int ni = 0; ni < 6; ++ni) {
        int nb   = n0 + wn * 96 + ni * 16;
        int nsel = nb >> 11;                // 0=q, 1=k, 2=v
        int nr   = nb & 2047;
        int h    = nr >> 7;
        int d    = (nr & 127) + r16;
        if (nsel < 2) {
            unsigned short* O = nsel ? Ok : Oq;
#pragma unroll
            for (int mi = 0; mi < 4; ++mi)
#pragma unroll
                for (int r = 0; r < 4; ++r) {
                    int m = m0 + wm * 64 + mi * 16 + q4 * 4 + r;
                    int b = m >> 11, l = m & 2047;
                    O[(((size_t)b * Hh + h) * Ll + l) * Hd + d] =
                        f2bf(acc[mi][ni][r]);
                }
        } else {
            // v: transposed store [b][h][d][l]; lane holds 4 consecutive l
#pragma unroll
            for (int mi = 0; mi < 4; ++mi) {
                int mb = m0 + wm * 64 + mi * 16 + q4 * 4;
                int b = mb >> 11, l = mb & 2047;
                ushort4 pk;
                pk.x = f2bf(acc[mi][ni][0]);
                pk.y = f2bf(acc[mi][ni][1]);
                pk.z = f2bf(acc[mi][ni][2]);
                pk.w = f2bf(acc[mi][ni][3]);
                *(ushort4*)&Ov[(((size_t)b * Hh + h) * Hd + d) * Ll + l] = pk;
            }
        }
    }
}

// ---------------------------------------------------------------------------
// Out-projection GEMM, R6-style 2-blocks/CU structure: C = A * W^T, fp32.
// BM=128 x BN=128, BK=64, 256 threads = 4 waves (2M x 2N), per-wave 64x64.
// LDS: 2 slots x 32 KiB = 64 KiB -> 2 blocks/CU, barrier-independent blocks
// cover each other's drains (m114).  Per K-tile: ks0 frags -> stage t+1
// (8 gld_lds/wave) -> 16 MFMA -> ks1 frags -> 16 MFMA -> vmcnt(0) -> barrier.
// XOR swizzle both-sides.  Grid 16x32 = 512 blocks = one round of 512.
// ---------------------------------------------------------------------------
__global__ __launch_bounds__(256, 2)
void mfma_gemm_out(const unsigned short* __restrict__ A,
                   const unsigned short* __restrict__ W,
                   float* __restrict__ FO)
{
    constexpr int K  = 2048;
    constexpr int NT = K / 64;              // 32 K-tiles
    constexpr int BM = 128, BN = 128;
    constexpr int SLOT_US = (BM + BN) * 64; // 16384 ushorts = 32 KiB

    __shared__ unsigned short lds[2 * SLOT_US];   // 64 KiB -> 2 blocks/CU

    const int t    = threadIdx.x;
    const int w    = t >> 6, lane = t & 63;
    const int wm   = w >> 1, wn = w & 1;          // 2M x 2N
    const int m0   = blockIdx.y * BM, n0 = blockIdx.x * BN;
    const int r16  = lane & 15, q4 = lane >> 4;
    const int lxor = (r16 & 7) << 4;

    const int srow8 = lane >> 3;
    const int sgcol = (((lane & 7) ^ srow8) << 4);
    const char* Agb = (const char*)A;
    const char* Wgb = (const char*)W;

    f32x4 acc[4][4];
#pragma unroll
    for (int i = 0; i < 4; ++i)
#pragma unroll
        for (int j = 0; j < 4; ++j)
            acc[i][j] = (f32x4){0.f, 0.f, 0.f, 0.f};

// stage full K-tile: A 16 gld (ia=w*4+p), B 16 gld (ib=w*4+p); 8 per wave
#define STAGE_ALL(tt, sl) do {                                               \
    _Pragma("unroll") for (int p = 0; p < 4; ++p) {                          \
        int ia_ = w * 4 + p;                                                 \
        gld16(Agb + (size_t)(m0 + ia_ * 8 + srow8) * (K * 2) + (tt) * 128 + sgcol, \
              &lds[(sl) * SLOT_US + ia_ * 512]);                             \
    }                                                                        \
    _Pragma("unroll") for (int p = 0; p < 4; ++p) {                          \
        int ib_ = w * 4 + p;                                                 \
        gld16(Wgb + (size_t)(n0 + ib_ * 8 + srow8) * (K * 2) + (tt) * 128 + sgcol, \
              &lds[(sl) * SLOT_US + BM * 64 + ib_ * 512]);                   \
    }                                                                        \
} while (0)

#define MFMA16() do {                                                        \
    __builtin_amdgcn_s_setprio(1);                                           \
    _Pragma("unroll") for (int mi = 0; mi < 4; ++mi)                         \
    _Pragma("unroll") for (int ni = 0; ni < 4; ++ni)                         \
        acc[mi][ni] = __builtin_amdgcn_mfma_f32_16x16x32_bf16(                \
            a[mi], b[ni], acc[mi][ni], 0, 0, 0);                             \
    __builtin_amdgcn_s_setprio(0);                                           \
} while (0)

    STAGE_ALL(0, 0);
    asm volatile("s_waitcnt vmcnt(0)" ::: "memory");
    __builtin_amdgcn_s_barrier();
    asm volatile("" ::: "memory");

    for (int tt = 0; tt < NT; ++tt) {
        const int slot = tt & 1;
        const char* Ab = (const char*)&lds[slot * SLOT_US];
        const char* Bp = (const char*)&lds[slot * SLOT_US + BM * 64];
        const int c0 = (q4 * 16) ^ lxor;
        const int c1 = (64 + q4 * 16) ^ lxor;

        s16x8 a[4], b[4];

#pragma unroll
        for (int mi = 0; mi < 4; ++mi)
            a[mi] = *(const s16x8*)(Ab + (wm * 64 + mi * 16 + r16) * 128 + c0);
#pragma unroll
        for (int ni = 0; ni < 4; ++ni)
            b[ni] = *(const s16x8*)(Bp + (wn * 64 + ni * 16 + r16) * 128 + c0);
        if (tt + 1 < NT) STAGE_ALL(tt + 1, slot ^ 1);
        MFMA16();

#pragma unroll
        for (int mi = 0; mi < 4; ++mi)
            a[mi] = *(const s16x8*)(Ab + (wm * 64 + mi * 16 + r16) * 128 + c1);
#pragma unroll
        for (int ni = 0; ni < 4; ++ni)
            b[ni] = *(const s16x8*)(Bp + (wn * 64 + ni * 16 + r16) * 128 + c1);
        MFMA16();

        asm volatile("s_waitcnt vmcnt(0)" ::: "memory");
        __builtin_amdgcn_s_barrier();
        asm volatile("" ::: "memory");
    }
#undef STAGE_ALL
#undef MFMA16

#pragma unroll
    for (int mi = 0; mi < 4; ++mi)
#pragma unroll
        for (int ni = 0; ni < 4; ++ni) {
            int n = n0 + wn * 64 + ni * 16 + r16;
#pragma unroll
            for (int r = 0; r < 4; ++r) {
                int m = m0 + wm * 64 + mi * 16 + q4 * 4 + r;
                FO[(size_t)m * Dd + n] = acc[mi][ni][r];
            }
        }
}

// ---------------------------------------------------------------------------
// RoPE in-place on bf16 q,k, vectorized short8 (G13).  16 threads/row,
// 16 rows/block; row lives in one wave.  q scaled by log2(e)/sqrt(128).
// grid: 8192 blocks (0..4095 = q, 4096..8191 = k).
// ---------------------------------------------------------------------------
__global__ __launch_bounds__(256)
void rope_bf16(unsigned short* __restrict__ q, unsigned short* __restrict__ k,
               const float* __restrict__ cosb, const float* __restrict__ sinb)
{
    const float QS = 0.1275175f;           // log2(e)/sqrt(128)
    const int t = threadIdx.x;
    int rblk = blockIdx.x;
    unsigned short* base;
    float sc;
    if (rblk < 4096) { base = q; sc = QS; }
    else             { base = k; sc = 1.0f; rblk -= 4096; }

    const int row = rblk * 16 + (t >> 4);  // [0, B*H*L)
    const int l   = row & (Ll - 1);
    const int d0  = (t & 15) * 8;
    unsigned short* xr = base + (size_t)row * Hd;

    s16x8 v0 = *(const s16x8*)(xr + d0);
    s16x8 vp = *(const s16x8*)(xr + (d0 ^ 64));
    const float* cp = cosb + (size_t)l * Hd + d0;
    const float* sp = sinb + (size_t)l * Hd + d0;
    float4 c0 = *(const float4*)cp,       c1 = *(const float4*)(cp + 4);
    float4 sa = *(const float4*)sp,       sb = *(const float4*)(sp + 4);
    const float cc[8] = {c0.x, c0.y, c0.z, c0.w, c1.x, c1.y, c1.z, c1.w};
    const float ss[8] = {sa.x, sa.y, sa.z, sa.w, sb.x, sb.y, sb.z, sb.w};
    const float sgn = (d0 < 64) ? -1.f : 1.f;

    s16x8 o;
#pragma unroll
    for (int j = 0; j < 8; ++j) {
        float a = bf2f((unsigned short)v0[j]);
        float p = bf2f((unsigned short)vp[j]);
        float res = fmaf(a, cc[j], sgn * p * ss[j]) * sc;
        o[j] = (short)f2bf(res);
    }
    asm volatile("" ::: "memory");         // loads (both halves) before store
    *(s16x8*)(xr + d0) = o;
}

// ---------------------------------------------------------------------------
// Flash attention (R3-proven, reverted from R9's 2-group regression):
// 32x32x16 bf16 MFMA, no-max softmax, double-buffered async gld_lds staging,
// XOR-swizzled linear LDS, one barrier per 64-key tile, setprio on MFMA.
// Block = 128 q-rows, 4 waves; LDS = 80 KiB -> 2 blocks/CU (the occupancy
// the 2-group variant lost; R9 showed that loss costs more than the
// read-amortization gains).
// ---------------------------------------------------------------------------
__global__ __launch_bounds__(256)
void flash_attn(const unsigned short* __restrict__ q,
                const unsigned short* __restrict__ k,
                const unsigned short* __restrict__ vT,
                unsigned short* __restrict__ ctx)
{
    __shared__ unsigned short Ks[2][64 * 128];   // [key][d] linear
    __shared__ unsigned short Vs[2][128 * 64];   // [d][key] linear
    __shared__ unsigned short Ps[4][32 * 64];    // per-wave [m][key]

    const int t = threadIdx.x;
    const int w = t >> 6, lane = t & 63;
    const int n32 = lane & 31, half = lane >> 5;
    const int bh = blockIdx.x >> 4;              // 16 q-tiles of 128 per (b,h)
    const int l0 = (blockIdx.x & 15) * 128;

    const unsigned short* qb = q  + ((size_t)bh * Ll + l0 + w * 32) * Hd;
    const unsigned short* kb = k  + (size_t)bh * Ll * Hd;
    const unsigned short* vb = vT + (size_t)bh * Hd * Ll;

    const int k_r = lane >> 4, k_u = lane & 15;  // K: 4 rows x 256 B per instr
    const int v_r = lane >> 3, v_u = lane & 7;   // V: 8 rows x 128 B per instr

#define STAGE(J0, bsel) do {                                                  \
    _Pragma("unroll") for (int p = 0; p < 4; ++p) {                           \
        int j_ = w * 4 + p;                                                   \
        int row_ = j_ * 4 + k_r;                                              \
        gld16(kb + (size_t)((J0) + row_) * Hd + ((k_u ^ (row_ & 7)) * 8),     \
              &Ks[bsel][j_ * 512]);                                           \
    }                                                                         \
    _Pragma("unroll") for (int p = 0; p < 4; ++p) {                           \
        int j_ = w * 4 + p;                                                   \
        int row_ = j_ * 8 + v_r;                                              \
        gld16(vb + (size_t)row_ * Ll + (J0) + ((v_u ^ (row_ & 7)) * 8),       \
              &Vs[bsel][j_ * 512]);                                           \
    }                                                                         \
} while (0)

    s16x8 qf[8];
#pragma unroll
    for (int ks = 0; ks < 8; ++ks)
        qf[ks] = *(const s16x8*)(qb + (size_t)n32 * Hd + ks * 16 + half * 8);

    f32x16 o[4];
    float lacc[16];
#pragma unroll
    for (int nt = 0; nt < 4; ++nt)
#pragma unroll
        for (int r = 0; r < 16; ++r) o[nt][r] = 0.f;
#pragma unroll
    for (int r = 0; r < 16; ++r) lacc[r] = 0.f;

    unsigned short* Pw = Ps[w];
    const int psw = (n32 & 7) << 3;              // read-side swizzle (row n32)

    STAGE(0, 0);
    __syncthreads();

    int buf = 0;
    for (int j0 = 0; j0 < Ll; j0 += 64) {
        if (j0 + 64 < Ll) STAGE(j0 + 64, buf ^ 1);   // in flight across compute

        f32x16 s0, s1;
#pragma unroll
        for (int r = 0; r < 16; ++r) { s0[r] = 0.f; s1[r] = 0.f; }
        __builtin_amdgcn_s_setprio(1);
#pragma unroll
        for (int ks = 0; ks < 8; ++ks) {
            int kc = (ks * 16 + half * 8) ^ psw;
            s16x8 b0 = *(const s16x8*)&Ks[buf][n32 * 128 + kc];
            s16x8 b1 = *(const s16x8*)&Ks[buf][(32 + n32) * 128 + kc];
            s0 = __builtin_amdgcn_mfma_f32_32x32x16_bf16(qf[ks], b0, s0, 0, 0, 0);
            s1 = __builtin_amdgcn_mfma_f32_32x32x16_bf16(qf[ks], b1, s1, 0, 0, 0);
        }
        __builtin_amdgcn_s_setprio(0);

#pragma unroll
        for (int r = 0; r < 16; ++r) {
            int mrow = (r & 3) + 8 * (r >> 2) + 4 * half;
            int sw = (mrow & 7) << 3;
            float p0 = fast_exp2(s0[r]);
            float p1 = fast_exp2(s1[r]);
            lacc[r] += p0 + p1;
            union { float f; unsigned u; } u0, u1;
            u0.f = p0; u1.f = p1;
            Pw[mrow * 64 + (n32 ^ sw)]        = (unsigned short)((u0.u + 0x8000u) >> 16);
            Pw[mrow * 64 + ((32 + n32) ^ sw)] = (unsigned short)((u1.u + 0x8000u) >> 16);
        }

        __builtin_amdgcn_s_setprio(1);
#pragma unroll
        for (int kst = 0; kst < 4; ++kst) {
            int cc = (kst * 16 + half * 8) ^ psw;
            s16x8 pf2 = *(const s16x8*)&Pw[n32 * 64 + cc];
#pragma unroll
            for (int nt = 0; nt < 4; ++nt) {
                s16x8 vf = *(const s16x8*)&Vs[buf][(nt * 32 + n32) * 64 + cc];
                o[nt] = __builtin_amdgcn_mfma_f32_32x32x16_bf16(pf2, vf, o[nt], 0, 0, 0);
            }
        }
        __builtin_amdgcn_s_setprio(0);

        __syncthreads();     // drains vmcnt(0): next tile staged; buffer swap
        buf ^= 1;
    }
#undef STAGE

    float linv[16];
#pragma unroll
    for (int r = 0; r < 16; ++r) {
        float s = lacc[r];
        s += __shfl_xor(s, 1, 64);
        s += __shfl_xor(s, 2, 64);
        s += __shfl_xor(s, 4, 64);
        s += __shfl_xor(s, 8, 64);
        s += __shfl_xor(s, 16, 64);
        linv[r] = 1.0f / s;
    }

    const int b = bh >> 4, h = bh & 15;
#pragma unroll
    for (int nt = 0; nt < 4; ++nt)
#pragma unroll
        for (int r = 0; r < 16; ++r) {
            int mrow = (r & 3) + 8 * (r >> 2) + 4 * half;
            int lq = l0 + w * 32 + mrow;
            ctx[((size_t)(b * Ll + lq)) * Dd + h * Hd + nt * 32 + n32] =
                f2bf(o[nt][r] * linv[r]);
        }
}

// ---------------------------------------------------------------------------
// Workspace (96 MB): [Xb 16M][Wq 8M][Wk 8M][Wv 8M][Wo 8M][q 16M][k 16M][vT 16M]
// Wq/Wk/Wv contiguous -> fused QKV GEMM reads them as one [6144][2048] W.
// ctx reuses the Xb slot (X dead after QKV GEMM).
// ---------------------------------------------------------------------------
extern "C" void kernel_launch(void* const* d_in, const int* in_sizes, int n_in,
                              void* d_out, int out_size, void* d_ws, size_t ws_size,
                              hipStream_t stream)
{
    const float* hs   = (const float*)d_in[0];
    const float* cosb = (const float*)d_in[1];
    const float* sinb = (const float*)d_in[2];
    const float* wq   = (const float*)d_in[3];
    const float* wk   = (const float*)d_in[4];
    const float* wv   = (const float*)d_in[5];
    const float* wo   = (const float*)d_in[6];
    float* out = (float*)d_out;

    char* ws = (char*)d_ws;
    unsigned short* Xb  = (unsigned short*)(ws);
    unsigned short* Wqb = (unsigned short*)(ws + (16ull << 20));
    unsigned short* Wkb = (unsigned short*)(ws + (24ull << 20));
    unsigned short* Wvb = (unsigned short*)(ws + (32ull << 20));
    unsigned short* Wob = (unsigned short*)(ws + (40ull << 20));
    unsigned short* qb  = (unsigned short*)(ws + (48ull << 20));
    unsigned short* kb  = (unsigned short*)(ws + (64ull << 20));
    unsigned short* vTb = (unsigned short*)(ws + (80ull << 20));
    unsigned short* ctx = Xb;

    // fp32 -> bf16, all tensors, one launch (24576 blocks)
    f2bf_all<<<dim3(24576), dim3(256), 0, stream>>>(
        hs, wq, wk, wv, wo, Xb, Wqb, Wkb, Wvb, Wob);

    // Fused QKV projection: A [4096x2048] x W [6144x2048]^T
    // BM=128 x BN=192: grid 32x32 = 1024 blocks, 2/CU co-resident, 2 rounds
    mfma_gemm_qkv<<<dim3(6144 / 192, M / 128), dim3(256), 0, stream>>>(
        Xb, Wqb, qb, kb, vTb);

    // RoPE: 16 rows/block, vectorized; blocks 0..4095 = q, 4096..8191 = k
    rope_bf16<<<dim3(2 * (Bb * Hh * Ll) / 16), dim3(256), 0, stream>>>(
        qb, kb, cosb, sinb);

    // Flash attention: 128 q-rows/block, 512 blocks (exactly 2/CU)
    flash_attn<<<dim3(Bb * Hh * (Ll / 128)), dim3(256), 0, stream>>>(qb, kb, vTb, ctx);

    // Output projection -> fp32 d_out
    // BM=128 x BN=128: grid 16x32 = 512 blocks = one round of 512, 2/CU
    mfma_gemm_out<<<dim3(Dd / 128, M / 128), dim3(256), 0, stream>>>(
        ctx, Wob, out);
}